// Round 3
// baseline (378.693 us; speedup 1.0000x reference)
//
#include <hip/hip_runtime.h>

#define DD 128
#define HH 64
#define RR 4
#define BM 64
#define NT 256

typedef __attribute__((ext_vector_type(8))) __bf16 bf16x8;
typedef __attribute__((ext_vector_type(4))) float f32x4;

// LDS row strides (bf16 elements); rows stay 16B-aligned, +8 pad rotates banks
#define LXS 136   // X / Msg rows (K=128 + 8)
#define LHS 72    // H1/H2 rows  (K=64 + 8)
// smem element offsets: H2 overlays H1 (wave-local, read-before-write in program order)
#define OXS 0
#define OH1 8704
#define SMEM_ELEMS 13312   // 26624 B -> 6 blocks/CU

// transposed bf16 weight pool offsets (elements)
#define W1T_OFF 0        // [R][64][128]
#define W2T_OFF 32768    // [R][64][64]
#define W3T_OFF 49152    // [R][128][64]
#define WPT_OFF 81920    // [R][64][128]  (Wn1 slice 1+r)
#define WN1_OFF 114688   // [64][128]     (Wn1 slice 0)
#define WN2_OFF 122880   // [64][64]
#define WN3_OFF 126976   // [128][64]
#define WT_TOTAL 135168

// ---------------- histograms: relation counts + destination counts ----------------
__global__ void k_hist(const int* __restrict__ et, const int* __restrict__ ed,
                       int* __restrict__ cnt, int* __restrict__ dstCnt, int E) {
    __shared__ int h[RR];
    int t = threadIdx.x;
    if (t < RR) h[t] = 0;
    __syncthreads();
    int i = blockIdx.x * blockDim.x + t;
    if (i < E) {
        atomicAdd(&h[et[i]], 1);
        atomicAdd(&dstCnt[ed[i]], 1);
    }
    __syncthreads();
    if (t < RR) atomicAdd(&cnt[t], h[t]);
}

// ---------------- scans: relation (serial, R=4) + dst CSR (block scan) ----------------
__global__ void k_scans(const int* __restrict__ cnt, int* __restrict__ segSt, int* __restrict__ cursor,
                        const int* __restrict__ dstCnt, int* __restrict__ rowStart,
                        int* __restrict__ dstCursor, int Nn) {
    __shared__ int part[1024];
    const int t = threadIdx.x;
    const int chunk = (Nn + 1023) / 1024;
    const int lo = t * chunk, hi = min(lo + chunk, Nn);
    int s = 0;
    for (int i = lo; i < hi; i++) s += dstCnt[i];
    part[t] = s;
    __syncthreads();
    for (int off = 1; off < 1024; off <<= 1) {
        int v = (t >= off) ? part[t - off] : 0;
        __syncthreads();
        part[t] += v;
        __syncthreads();
    }
    int run = (t > 0) ? part[t - 1] : 0;
    for (int i = lo; i < hi; i++) {
        rowStart[i] = run;
        dstCursor[i] = run;
        run += dstCnt[i];
    }
    if (t == 1023) rowStart[Nn] = part[1023];
    if (t == 0) {
        int s2 = 0;
        for (int r = 0; r < RR; r++) { segSt[r] = s2; cursor[r] = s2; s2 += cnt[r]; }
    }
}

// ---------------- placement: relation-sorted perm + dst-CSR slot per edge ----------------
__global__ void k_place(const int* __restrict__ et, const int* __restrict__ ed,
                        int* __restrict__ cursor, int* __restrict__ dstCursor,
                        int* __restrict__ perm, int* __restrict__ slot, int E) {
    __shared__ int h[RR];
    __shared__ int baseS[RR];
    int t = threadIdx.x;
    if (t < RR) h[t] = 0;
    __syncthreads();
    int i = blockIdx.x * blockDim.x + t;
    int r = 0, pos = 0;
    if (i < E) {
        r = et[i];
        pos = atomicAdd(&h[r], 1);
        slot[i] = atomicAdd(&dstCursor[ed[i]], 1);
    }
    __syncthreads();
    if (t < RR) baseS[t] = atomicAdd(&cursor[t], h[t]);
    __syncthreads();
    if (i < E) perm[baseS[r] + pos] = i;
}

// ---------------- weight transpose+convert ----------------
__global__ void k_prep(const float* __restrict__ Wr1, const float* __restrict__ Wr2,
                       const float* __restrict__ Wr3, const float* __restrict__ Wn1,
                       const float* __restrict__ Wn2, const float* __restrict__ Wn3,
                       __bf16* __restrict__ wt) {
    int i = blockIdx.x * blockDim.x + threadIdx.x;
    float v;
    if (i < 32768) {                       // W1t [r][n64][k128]
        int r = i >> 13, n = (i >> 7) & 63, k = i & 127;
        v = Wr1[r * 8192 + k * 64 + n];
    } else if (i < 49152) {                // W2t [r][n64][k64]
        int j = i - 32768; int r = j >> 12, n = (j >> 6) & 63, k = j & 63;
        v = Wr2[r * 4096 + k * 64 + n];
    } else if (i < 81920) {                // W3t [r][n128][k64]
        int j = i - 49152; int r = j >> 13, n = (j >> 6) & 127, k = j & 63;
        v = Wr3[r * 8192 + k * 128 + n];
    } else if (i < 114688) {               // Wpt [r][n64][k128]
        int j = i - 81920; int r = j >> 13, n = (j >> 7) & 63, k = j & 127;
        v = Wn1[((1 + r) * 128 + k) * 64 + n];
    } else if (i < 122880) {               // Wn1t0 [n64][k128]
        int j = i - 114688; int n = j >> 7, k = j & 127;
        v = Wn1[k * 64 + n];
    } else if (i < 126976) {               // Wn2t [n64][k64]
        int j = i - 122880; int n = j >> 6, k = j & 63;
        v = Wn2[k * 64 + n];
    } else if (i < WT_TOTAL) {             // Wn3t [n128][k64]
        int j = i - 126976; int n = j >> 6, k = j & 63;
        v = Wn3[k * 128 + n];
    } else return;
    wt[i] = (__bf16)v;
}

// ---------------- edge message pipeline (MFMA, barrier-free, atomic-free) ----------------
__global__ __launch_bounds__(NT, 6) void k_edge(
    const float* __restrict__ nf, const int* __restrict__ es,
    const float* __restrict__ br1, const float* __restrict__ br2, const float* __restrict__ br3,
    const __bf16* __restrict__ wt,
    const int* __restrict__ perm, const int* __restrict__ segStart, const int* __restrict__ cnt,
    const int* __restrict__ slot, __bf16* __restrict__ cbuf)
{
    __shared__ __bf16 smem[SMEM_ELEMS];
    __bf16* Xs = smem + OXS;   // [64][LXS]
    __bf16* H1 = smem + OH1;   // [64][LHS]
    __bf16* H2 = smem + OH1;   // overlays H1 (wave-local rows, read-then-write)
    __bf16* Ms = smem + OXS;   // overlays Xs (dead after GEMM1)

    const int r = blockIdx.y;
    const int len = cnt[r];
    const int tile = blockIdx.x;
    if (tile * BM >= len) return;
    const int base = segStart[r] + tile * BM;
    const int mcount = min(BM, len - tile * BM);
    const int tid = threadIdx.x;
    const int w = tid >> 6;
    const int lane = tid & 63;
    const int ln = lane & 15, qd = lane >> 4;
    const int m0 = w << 4;     // wave-owned m-tile: rows m0..m0+15

    // ---- stage X rows (wave-local: thread t handles row t>>2 in its own tile)
    {
        const int m = tid >> 2, q = tid & 3;
        int srcn = 0;
        if (m < mcount) srcn = es[perm[base + m]];
        const float4* rp = (const float4*)(nf + (size_t)srcn * DD) + 8 * q;
        __bf16* xr = Xs + m * LXS + 32 * q;
        #pragma unroll
        for (int jj = 0; jj < 4; jj++) {
            float4 v0 = rp[2 * jj], v1 = rp[2 * jj + 1];
            bf16x8 p;
            p[0] = (__bf16)v0.x; p[1] = (__bf16)v0.y; p[2] = (__bf16)v0.z; p[3] = (__bf16)v0.w;
            p[4] = (__bf16)v1.x; p[5] = (__bf16)v1.y; p[6] = (__bf16)v1.z; p[7] = (__bf16)v1.w;
            *(bf16x8*)(xr + 8 * jj) = p;
        }
    }

    // ---- GEMM1: h1 = relu(X @ W1 + b1)   M64 N64 K128
    {
        const __bf16* W1t = wt + W1T_OFF + r * 8192;
        f32x4 c[4] = {};
        #pragma unroll
        for (int ks = 0; ks < 128; ks += 32) {
            bf16x8 a = *(const bf16x8*)(Xs + (m0 + ln) * LXS + ks + 8 * qd);
            #pragma unroll
            for (int nt = 0; nt < 4; nt++) {
                bf16x8 b = *(const bf16x8*)(W1t + (nt * 16 + ln) * 128 + ks + 8 * qd);
                c[nt] = __builtin_amdgcn_mfma_f32_16x16x32_bf16(a, b, c[nt], 0, 0, 0);
            }
        }
        #pragma unroll
        for (int nt = 0; nt < 4; nt++) {
            float bv = br1[r * HH + nt * 16 + ln];
            #pragma unroll
            for (int rg = 0; rg < 4; rg++) {
                float v = c[nt][rg] + bv;
                H1[(m0 + qd * 4 + rg) * LHS + nt * 16 + ln] = (__bf16)fmaxf(v, 0.f);
            }
        }
    }

    // ---- GEMM2: h2 = relu(h1 @ W2 + b2)  M64 N64 K64  (A preloaded; H2 overlays H1)
    {
        const __bf16* W2t = wt + W2T_OFF + r * 4096;
        bf16x8 a0 = *(const bf16x8*)(H1 + (m0 + ln) * LHS + 0 + 8 * qd);
        bf16x8 a1 = *(const bf16x8*)(H1 + (m0 + ln) * LHS + 32 + 8 * qd);
        f32x4 c[4] = {};
        #pragma unroll
        for (int nt = 0; nt < 4; nt++) {
            bf16x8 b0 = *(const bf16x8*)(W2t + (nt * 16 + ln) * 64 + 0 + 8 * qd);
            bf16x8 b1 = *(const bf16x8*)(W2t + (nt * 16 + ln) * 64 + 32 + 8 * qd);
            c[nt] = __builtin_amdgcn_mfma_f32_16x16x32_bf16(a0, b0, c[nt], 0, 0, 0);
            c[nt] = __builtin_amdgcn_mfma_f32_16x16x32_bf16(a1, b1, c[nt], 0, 0, 0);
        }
        #pragma unroll
        for (int nt = 0; nt < 4; nt++) {
            float bv = br2[r * HH + nt * 16 + ln];
            #pragma unroll
            for (int rg = 0; rg < 4; rg++) {
                float v = c[nt][rg] + bv;
                H2[(m0 + qd * 4 + rg) * LHS + nt * 16 + ln] = (__bf16)fmaxf(v, 0.f);
            }
        }
    }

    // ---- GEMM3: msg = relu(h2 @ W3 + b3)  M64 N128 K64 -> Ms (overlays Xs)
    {
        const __bf16* W3t = wt + W3T_OFF + r * 8192;
        bf16x8 a0 = *(const bf16x8*)(H2 + (m0 + ln) * LHS + 0 + 8 * qd);
        bf16x8 a1 = *(const bf16x8*)(H2 + (m0 + ln) * LHS + 32 + 8 * qd);
        f32x4 c[8] = {};
        #pragma unroll
        for (int nt = 0; nt < 8; nt++) {
            bf16x8 b0 = *(const bf16x8*)(W3t + (nt * 16 + ln) * 64 + 0 + 8 * qd);
            bf16x8 b1 = *(const bf16x8*)(W3t + (nt * 16 + ln) * 64 + 32 + 8 * qd);
            c[nt] = __builtin_amdgcn_mfma_f32_16x16x32_bf16(a0, b0, c[nt], 0, 0, 0);
            c[nt] = __builtin_amdgcn_mfma_f32_16x16x32_bf16(a1, b1, c[nt], 0, 0, 0);
        }
        #pragma unroll
        for (int nt = 0; nt < 8; nt++) {
            float bv = br3[r * DD + nt * 16 + ln];
            #pragma unroll
            for (int rg = 0; rg < 4; rg++) {
                float v = c[nt][rg] + bv;
                Ms[(m0 + qd * 4 + rg) * LXS + nt * 16 + ln] = (__bf16)fmaxf(v, 0.f);
            }
        }
    }

    // ---- PROJ: contrib = msg @ Wn1_slice(1+r)  M64 N64 K128 -> CSR slot (plain stores)
    {
        const __bf16* Wpt = wt + WPT_OFF + r * 8192;
        f32x4 c[4] = {};
        #pragma unroll
        for (int ks = 0; ks < 128; ks += 32) {
            bf16x8 a = *(const bf16x8*)(Ms + (m0 + ln) * LXS + ks + 8 * qd);
            #pragma unroll
            for (int nt = 0; nt < 4; nt++) {
                bf16x8 b = *(const bf16x8*)(Wpt + (nt * 16 + ln) * 128 + ks + 8 * qd);
                c[nt] = __builtin_amdgcn_mfma_f32_16x16x32_bf16(a, b, c[nt], 0, 0, 0);
            }
        }
        #pragma unroll
        for (int rg = 0; rg < 4; rg++) {
            const int m = m0 + qd * 4 + rg;
            if (m < mcount) {
                const int sl = slot[perm[base + m]];
                __bf16* cp = cbuf + (size_t)sl * HH;
                #pragma unroll
                for (int nt = 0; nt < 4; nt++)
                    cp[nt * 16 + ln] = (__bf16)c[nt][rg];
            }
        }
    }
}

// ---------------- node updater MLP (MFMA, barrier-free; CSR gather of contribs) ----------------
__global__ __launch_bounds__(NT, 4) void k_node(
    const float* __restrict__ nf,
    const float* __restrict__ bn1, const float* __restrict__ bn2, const float* __restrict__ bn3,
    const __bf16* __restrict__ wt, const __bf16* __restrict__ cbuf,
    const int* __restrict__ rowStart,
    float* __restrict__ out, int Nn)
{
    __shared__ __bf16 smem[SMEM_ELEMS];
    __bf16* Xs = smem + OXS;
    __bf16* H1 = smem + OH1;
    __bf16* H2 = smem + OH1;   // overlays H1

    const int nb0 = blockIdx.x * BM;
    const int mcount = min(BM, Nn - nb0);
    const int tid = threadIdx.x;
    const int w = tid >> 6;
    const int lane = tid & 63;
    const int ln = lane & 15, qd = lane >> 4;
    const int m0 = w << 4;

    // stage relu(node_feature) rows (wave-local)
    {
        const int m = tid >> 2, q = tid & 3;
        const int node = nb0 + ((m < mcount) ? m : 0);
        const float4* rp = (const float4*)(nf + (size_t)node * DD) + 8 * q;
        __bf16* xr = Xs + m * LXS + 32 * q;
        #pragma unroll
        for (int jj = 0; jj < 4; jj++) {
            float4 v0 = rp[2 * jj], v1 = rp[2 * jj + 1];
            bf16x8 p;
            p[0] = (__bf16)fmaxf(v0.x, 0.f); p[1] = (__bf16)fmaxf(v0.y, 0.f);
            p[2] = (__bf16)fmaxf(v0.z, 0.f); p[3] = (__bf16)fmaxf(v0.w, 0.f);
            p[4] = (__bf16)fmaxf(v1.x, 0.f); p[5] = (__bf16)fmaxf(v1.y, 0.f);
            p[6] = (__bf16)fmaxf(v1.z, 0.f); p[7] = (__bf16)fmaxf(v1.w, 0.f);
            *(bf16x8*)(xr + 8 * jj) = p;
        }
    }

    // gather+sum CSR contribs: agg[rg][nt] for this lane's columns
    float agg[4][4] = {};
    #pragma unroll
    for (int rg = 0; rg < 4; rg++) {
        const int m = m0 + qd * 4 + rg;
        if (m < mcount) {
            const int node = nb0 + m;
            const int s0 = rowStart[node], s1 = rowStart[node + 1];
            for (int s = s0; s < s1; s++) {
                const __bf16* cp = cbuf + (size_t)s * HH + ln;
                agg[rg][0] += (float)cp[0];
                agg[rg][1] += (float)cp[16];
                agg[rg][2] += (float)cp[32];
                agg[rg][3] += (float)cp[48];
            }
        }
    }

    // GEMM1n: h = relu(relu(X) @ Wn1_0 + agg + bn1)  K128 N64
    {
        const __bf16* Wt = wt + WN1_OFF;
        f32x4 c[4] = {};
        #pragma unroll
        for (int ks = 0; ks < 128; ks += 32) {
            bf16x8 a = *(const bf16x8*)(Xs + (m0 + ln) * LXS + ks + 8 * qd);
            #pragma unroll
            for (int nt = 0; nt < 4; nt++) {
                bf16x8 b = *(const bf16x8*)(Wt + (nt * 16 + ln) * 128 + ks + 8 * qd);
                c[nt] = __builtin_amdgcn_mfma_f32_16x16x32_bf16(a, b, c[nt], 0, 0, 0);
            }
        }
        #pragma unroll
        for (int nt = 0; nt < 4; nt++) {
            float bv = bn1[nt * 16 + ln];
            #pragma unroll
            for (int rg = 0; rg < 4; rg++) {
                float v = c[nt][rg] + bv + agg[rg][nt];
                H1[(m0 + qd * 4 + rg) * LHS + nt * 16 + ln] = (__bf16)fmaxf(v, 0.f);
            }
        }
    }

    // GEMM2n: K64 N64 (A preloaded; H2 overlays H1)
    {
        const __bf16* Wt = wt + WN2_OFF;
        bf16x8 a0 = *(const bf16x8*)(H1 + (m0 + ln) * LHS + 0 + 8 * qd);
        bf16x8 a1 = *(const bf16x8*)(H1 + (m0 + ln) * LHS + 32 + 8 * qd);
        f32x4 c[4] = {};
        #pragma unroll
        for (int nt = 0; nt < 4; nt++) {
            bf16x8 b0 = *(const bf16x8*)(Wt + (nt * 16 + ln) * 64 + 0 + 8 * qd);
            bf16x8 b1 = *(const bf16x8*)(Wt + (nt * 16 + ln) * 64 + 32 + 8 * qd);
            c[nt] = __builtin_amdgcn_mfma_f32_16x16x32_bf16(a0, b0, c[nt], 0, 0, 0);
            c[nt] = __builtin_amdgcn_mfma_f32_16x16x32_bf16(a1, b1, c[nt], 0, 0, 0);
        }
        #pragma unroll
        for (int nt = 0; nt < 4; nt++) {
            float bv = bn2[nt * 16 + ln];
            #pragma unroll
            for (int rg = 0; rg < 4; rg++) {
                float v = c[nt][rg] + bv;
                H2[(m0 + qd * 4 + rg) * LHS + nt * 16 + ln] = (__bf16)fmaxf(v, 0.f);
            }
        }
    }

    // GEMM3n: K64 N128 -> out (+bn3, no relu)
    {
        const __bf16* Wt = wt + WN3_OFF;
        bf16x8 a0 = *(const bf16x8*)(H2 + (m0 + ln) * LHS + 0 + 8 * qd);
        bf16x8 a1 = *(const bf16x8*)(H2 + (m0 + ln) * LHS + 32 + 8 * qd);
        f32x4 c[8] = {};
        #pragma unroll
        for (int nt = 0; nt < 8; nt++) {
            bf16x8 b0 = *(const bf16x8*)(Wt + (nt * 16 + ln) * 64 + 0 + 8 * qd);
            bf16x8 b1 = *(const bf16x8*)(Wt + (nt * 16 + ln) * 64 + 32 + 8 * qd);
            c[nt] = __builtin_amdgcn_mfma_f32_16x16x32_bf16(a0, b0, c[nt], 0, 0, 0);
            c[nt] = __builtin_amdgcn_mfma_f32_16x16x32_bf16(a1, b1, c[nt], 0, 0, 0);
        }
        #pragma unroll
        for (int rg = 0; rg < 4; rg++) {
            const int m = m0 + qd * 4 + rg;
            if (m < mcount) {
                float* op = out + (size_t)(nb0 + m) * DD;
                #pragma unroll
                for (int nt = 0; nt < 8; nt++)
                    op[nt * 16 + ln] = c[nt][rg] + bn3[nt * 16 + ln];
            }
        }
    }
}

extern "C" void kernel_launch(void* const* d_in, const int* in_sizes, int n_in,
                              void* d_out, int out_size, void* d_ws, size_t ws_size,
                              hipStream_t stream) {
    const float* nf  = (const float*)d_in[0];
    const int*   es  = (const int*)d_in[1];
    const int*   ed  = (const int*)d_in[2];
    const int*   et  = (const int*)d_in[3];
    const float* Wr1 = (const float*)d_in[4];
    const float* br1 = (const float*)d_in[5];
    const float* Wr2 = (const float*)d_in[6];
    const float* br2 = (const float*)d_in[7];
    const float* Wr3 = (const float*)d_in[8];
    const float* br3 = (const float*)d_in[9];
    const float* Wn1 = (const float*)d_in[10];
    const float* bn1 = (const float*)d_in[11];
    const float* Wn2 = (const float*)d_in[12];
    const float* bn2 = (const float*)d_in[13];
    const float* Wn3 = (const float*)d_in[14];
    const float* bn3 = (const float*)d_in[15];
    float* out = (float*)d_out;

    const int Nn = in_sizes[0] / DD;   // 50000
    const int E  = in_sizes[1];        // 200000

    // workspace layout (ints unless noted)
    int* p = (int*)d_ws;
    int* perm      = p;                 p += E;
    int* slot      = p;                 p += E;
    int* cnt       = p;                 p += RR;      // ---- zero region start
    int* segSt     = p;                 p += RR;
    int* cursor    = p;                 p += RR;
    int* dstCnt    = p;                 p += Nn;
    int* dstCursor = p;                 p += Nn;      // ---- zero region end
    int* rowStart  = p;                 p += Nn + 1;
    p += ((8 - ((p - (int*)d_ws) & 7)) & 7);          // 32B-align
    __bf16* wbf  = (__bf16*)p;          p += (WT_TOTAL + 1) / 2;
    __bf16* cbuf = (__bf16*)p;                         // E*HH bf16 = 25.6 MB

    const size_t zbytes = (size_t)(3 * RR + 2 * Nn) * sizeof(int);
    hipMemsetAsync((void*)cnt, 0, zbytes, stream);

    const int nb = (E + NT - 1) / NT;
    k_hist  <<<nb, NT, 0, stream>>>(et, ed, cnt, dstCnt, E);
    k_scans <<<1, 1024, 0, stream>>>(cnt, segSt, cursor, dstCnt, rowStart, dstCursor, Nn);
    k_place <<<nb, NT, 0, stream>>>(et, ed, cursor, dstCursor, perm, slot, E);
    k_prep  <<<(WT_TOTAL + NT - 1) / NT, NT, 0, stream>>>(Wr1, Wr2, Wr3, Wn1, Wn2, Wn3, wbf);

    dim3 ge((E + BM - 1) / BM, RR);
    k_edge<<<ge, NT, 0, stream>>>(nf, es, br1, br2, br3, wbf, perm, segSt, cnt, slot, cbuf);
    k_node<<<(Nn + BM - 1) / BM, NT, 0, stream>>>(nf, bn1, bn2, bn3, wbf, cbuf, rowStart, out, Nn);
}

// Round 4
// 292.287 us; speedup vs baseline: 1.2956x; 1.2956x over previous
//
#include <hip/hip_runtime.h>

#define DD 128
#define HH 64
#define RR 4
#define BM 64
#define NT 256

typedef __attribute__((ext_vector_type(8))) __bf16 bf16x8;
typedef __attribute__((ext_vector_type(4))) float f32x4;

// Per-wave LDS block: all stage buffers overlay inside one wave-private region.
// Xs [16][LXS] -> H1 [16][LHS] (after GEMM1 reads) -> H2 overlays H1 -> Ms [16][LXS].
// Wave-local DS ops are in-order; reads of a stage complete (regs) before overwrite.
#define LXS 136   // X / Msg row stride (K=128 + 8 pad)
#define LHS 72    // H1/H2 row stride  (K=64 + 8 pad)
#define WBLK 2176 // 16*LXS elements per wave
#define SMEM_ELEMS 8704   // 4 waves -> 17408 B -> 8 blocks/CU

// transposed bf16 weight pool offsets (elements)
#define W1T_OFF 0        // [R][64][128]
#define W2T_OFF 32768    // [R][64][64]
#define W3T_OFF 49152    // [R][128][64]
#define WPT_OFF 81920    // [R][64][128]  (Wn1 slice 1+r)
#define WN1_OFF 114688   // [64][128]     (Wn1 slice 0)
#define WN2_OFF 122880   // [64][64]
#define WN3_OFF 126976   // [128][64]
#define WT_TOTAL 135168

// ---------------- histograms: relation counts + destination counts ----------------
__global__ void k_hist(const int* __restrict__ et, const int* __restrict__ ed,
                       int* __restrict__ cnt, int* __restrict__ dstCnt, int E) {
    __shared__ int h[RR];
    int t = threadIdx.x;
    if (t < RR) h[t] = 0;
    __syncthreads();
    int i = blockIdx.x * blockDim.x + t;
    if (i < E) {
        atomicAdd(&h[et[i]], 1);
        atomicAdd(&dstCnt[ed[i]], 1);
    }
    __syncthreads();
    if (t < RR) atomicAdd(&cnt[t], h[t]);
}

// ---------------- parallel CSR scan: pass 1 (per-1024-chunk block sums) ----------------
__global__ void k_bsum(const int* __restrict__ dstCnt, int* __restrict__ blkSum, int Nn) {
    int b = blockIdx.x, t = threadIdx.x;
    int g = b * 1024 + t * 4;
    int s = 0;
    if (g + 3 < Nn) { int4 v = *(const int4*)(dstCnt + g); s = v.x + v.y + v.z + v.w; }
    else { for (int k = 0; k < 4; k++) if (g + k < Nn) s += dstCnt[g + k]; }
    for (int off = 32; off > 0; off >>= 1) s += __shfl_down(s, off);
    __shared__ int ws[4];
    if ((t & 63) == 0) ws[t >> 6] = s;
    __syncthreads();
    if (t == 0) blkSum[b] = ws[0] + ws[1] + ws[2] + ws[3];
}

// ---------------- pass 2: one wave scans block sums (NB<=64) + relation scan ----------------
__global__ void k_mid(const int* __restrict__ cnt, int* __restrict__ segSt, int* __restrict__ cursor,
                      const int* __restrict__ blkSum, int* __restrict__ blkOff,
                      int* __restrict__ rowStart, int NB, int Nn, int E) {
    int lane = threadIdx.x;
    int s = (lane < NB) ? blkSum[lane] : 0;
    int sc = s;
    #pragma unroll
    for (int off = 1; off < 64; off <<= 1) { int u = __shfl_up(sc, off); if (lane >= off) sc += u; }
    if (lane < NB) blkOff[lane] = sc - s;
    if (lane == 0) {
        int s2 = 0;
        for (int r = 0; r < RR; r++) { segSt[r] = s2; cursor[r] = s2; s2 += cnt[r]; }
        rowStart[Nn] = E;
    }
}

// ---------------- pass 3: write exclusive prefix (rowStart + dstCursor) ----------------
__global__ void k_wout(const int* __restrict__ dstCnt, const int* __restrict__ blkOff,
                       int* __restrict__ rowStart, int* __restrict__ dstCursor, int Nn) {
    int b = blockIdx.x, t = threadIdx.x;
    int g = b * 1024 + t * 4;
    int4 v = {0, 0, 0, 0};
    bool full = (g + 3 < Nn);
    if (full) v = *(const int4*)(dstCnt + g);
    else {
        if (g     < Nn) v.x = dstCnt[g];
        if (g + 1 < Nn) v.y = dstCnt[g + 1];
        if (g + 2 < Nn) v.z = dstCnt[g + 2];
    }
    int s = v.x + v.y + v.z + v.w;
    int lane = t & 63, wv = t >> 6;
    int sc = s;
    #pragma unroll
    for (int off = 1; off < 64; off <<= 1) { int u = __shfl_up(sc, off); if (lane >= off) sc += u; }
    __shared__ int wsum[4];
    if (lane == 63) wsum[wv] = sc;
    __syncthreads();
    int wadd = 0;
    for (int i = 0; i < wv; i++) wadd += wsum[i];
    int e0 = blkOff[b] + wadd + sc - s;
    int4 rs; rs.x = e0; rs.y = e0 + v.x; rs.z = rs.y + v.y; rs.w = rs.z + v.z;
    if (full) { *(int4*)(rowStart + g) = rs; *(int4*)(dstCursor + g) = rs; }
    else {
        int a[4] = {rs.x, rs.y, rs.z, rs.w};
        for (int k = 0; k < 4; k++) if (g + k < Nn) { rowStart[g + k] = a[k]; dstCursor[g + k] = a[k]; }
    }
}

// ---------------- placement: value-permuted src + CSR slot per edge ----------------
__global__ void k_place(const int* __restrict__ et, const int* __restrict__ ed,
                        const int* __restrict__ es,
                        int* __restrict__ cursor, int* __restrict__ dstCursor,
                        int* __restrict__ esPerm, int* __restrict__ slotPerm, int E) {
    __shared__ int h[RR];
    __shared__ int baseS[RR];
    int t = threadIdx.x;
    if (t < RR) h[t] = 0;
    __syncthreads();
    int i = blockIdx.x * blockDim.x + t;
    int r = 0, pos = 0, sl = 0, sv = 0;
    if (i < E) {
        r = et[i];
        pos = atomicAdd(&h[r], 1);
        sl = atomicAdd(&dstCursor[ed[i]], 1);
        sv = es[i];
    }
    __syncthreads();
    if (t < RR) baseS[t] = atomicAdd(&cursor[t], h[t]);
    __syncthreads();
    if (i < E) { int j = baseS[r] + pos; esPerm[j] = sv; slotPerm[j] = sl; }
}

// ---------------- weight transpose+convert ----------------
__global__ void k_prep(const float* __restrict__ Wr1, const float* __restrict__ Wr2,
                       const float* __restrict__ Wr3, const float* __restrict__ Wn1,
                       const float* __restrict__ Wn2, const float* __restrict__ Wn3,
                       __bf16* __restrict__ wt) {
    int i = blockIdx.x * blockDim.x + threadIdx.x;
    float v;
    if (i < 32768) {                       // W1t [r][n64][k128]
        int r = i >> 13, n = (i >> 7) & 63, k = i & 127;
        v = Wr1[r * 8192 + k * 64 + n];
    } else if (i < 49152) {                // W2t [r][n64][k64]
        int j = i - 32768; int r = j >> 12, n = (j >> 6) & 63, k = j & 63;
        v = Wr2[r * 4096 + k * 64 + n];
    } else if (i < 81920) {                // W3t [r][n128][k64]
        int j = i - 49152; int r = j >> 13, n = (j >> 6) & 127, k = j & 63;
        v = Wr3[r * 8192 + k * 128 + n];
    } else if (i < 114688) {               // Wpt [r][n64][k128]
        int j = i - 81920; int r = j >> 13, n = (j >> 7) & 63, k = j & 127;
        v = Wn1[((1 + r) * 128 + k) * 64 + n];
    } else if (i < 122880) {               // Wn1t0 [n64][k128]
        int j = i - 114688; int n = j >> 7, k = j & 127;
        v = Wn1[k * 64 + n];
    } else if (i < 126976) {               // Wn2t [n64][k64]
        int j = i - 122880; int n = j >> 6, k = j & 63;
        v = Wn2[k * 64 + n];
    } else if (i < WT_TOTAL) {             // Wn3t [n128][k64]
        int j = i - 126976; int n = j >> 6, k = j & 63;
        v = Wn3[k * 128 + n];
    } else return;
    wt[i] = (__bf16)v;
}

// ---------------- edge message pipeline (MFMA, barrier-free, atomic-free) ----------------
__global__ __launch_bounds__(NT, 8) void k_edge(
    const float* __restrict__ nf,
    const float* __restrict__ br1, const float* __restrict__ br2, const float* __restrict__ br3,
    const __bf16* __restrict__ wt,
    const int* __restrict__ esPerm, const int* __restrict__ slotPerm,
    const int* __restrict__ segStart, const int* __restrict__ cnt,
    __bf16* __restrict__ cbuf)
{
    __shared__ __bf16 smem[SMEM_ELEMS];

    const int r = blockIdx.y;
    const int len = cnt[r];
    const int tile = blockIdx.x;
    if (tile * BM >= len) return;
    const int base = segStart[r] + tile * BM;
    const int mcount = min(BM, len - tile * BM);
    const int tid = threadIdx.x;
    const int w = tid >> 6;
    const int lane = tid & 63;
    const int ln = lane & 15, qd = lane >> 4;
    __bf16* Wb = smem + w * WBLK;   // this wave's private block

    // ---- stage X rows (wave-local: thread t handles row t>>2)
    {
        const int m = tid >> 2, q = tid & 3;
        int srcn = 0;
        if (m < mcount) srcn = esPerm[base + m];
        const float4* rp = (const float4*)(nf + (size_t)srcn * DD) + 8 * q;
        __bf16* xr = Wb + (m & 15) * LXS + 32 * q;
        #pragma unroll
        for (int jj = 0; jj < 4; jj++) {
            float4 v0 = rp[2 * jj], v1 = rp[2 * jj + 1];
            bf16x8 p;
            p[0] = (__bf16)v0.x; p[1] = (__bf16)v0.y; p[2] = (__bf16)v0.z; p[3] = (__bf16)v0.w;
            p[4] = (__bf16)v1.x; p[5] = (__bf16)v1.y; p[6] = (__bf16)v1.z; p[7] = (__bf16)v1.w;
            *(bf16x8*)(xr + 8 * jj) = p;
        }
    }

    // ---- GEMM1: h1 = relu(X @ W1 + b1)   M16/wave N64 K128
    {
        const __bf16* W1t = wt + W1T_OFF + r * 8192;
        f32x4 c[4] = {};
        #pragma unroll
        for (int ks = 0; ks < 128; ks += 32) {
            bf16x8 a = *(const bf16x8*)(Wb + ln * LXS + ks + 8 * qd);
            #pragma unroll
            for (int nt = 0; nt < 4; nt++) {
                bf16x8 b = *(const bf16x8*)(W1t + (nt * 16 + ln) * 128 + ks + 8 * qd);
                c[nt] = __builtin_amdgcn_mfma_f32_16x16x32_bf16(a, b, c[nt], 0, 0, 0);
            }
        }
        #pragma unroll
        for (int nt = 0; nt < 4; nt++) {
            float bv = br1[r * HH + nt * 16 + ln];
            #pragma unroll
            for (int rg = 0; rg < 4; rg++) {
                float v = c[nt][rg] + bv;
                Wb[(qd * 4 + rg) * LHS + nt * 16 + ln] = (__bf16)fmaxf(v, 0.f);  // H1 overlays Xs
            }
        }
    }

    // ---- GEMM2: h2 = relu(h1 @ W2 + b2)  K64 (A preloaded; H2 overlays H1)
    {
        const __bf16* W2t = wt + W2T_OFF + r * 4096;
        bf16x8 a0 = *(const bf16x8*)(Wb + ln * LHS + 0 + 8 * qd);
        bf16x8 a1 = *(const bf16x8*)(Wb + ln * LHS + 32 + 8 * qd);
        f32x4 c[4] = {};
        #pragma unroll
        for (int nt = 0; nt < 4; nt++) {
            bf16x8 b0 = *(const bf16x8*)(W2t + (nt * 16 + ln) * 64 + 0 + 8 * qd);
            bf16x8 b1 = *(const bf16x8*)(W2t + (nt * 16 + ln) * 64 + 32 + 8 * qd);
            c[nt] = __builtin_amdgcn_mfma_f32_16x16x32_bf16(a0, b0, c[nt], 0, 0, 0);
            c[nt] = __builtin_amdgcn_mfma_f32_16x16x32_bf16(a1, b1, c[nt], 0, 0, 0);
        }
        #pragma unroll
        for (int nt = 0; nt < 4; nt++) {
            float bv = br2[r * HH + nt * 16 + ln];
            #pragma unroll
            for (int rg = 0; rg < 4; rg++) {
                float v = c[nt][rg] + bv;
                Wb[(qd * 4 + rg) * LHS + nt * 16 + ln] = (__bf16)fmaxf(v, 0.f);  // H2
            }
        }
    }

    // ---- GEMM3: msg = relu(h2 @ W3 + b3)  N128 K64 -> Ms (overlays whole block)
    {
        const __bf16* W3t = wt + W3T_OFF + r * 8192;
        bf16x8 a0 = *(const bf16x8*)(Wb + ln * LHS + 0 + 8 * qd);
        bf16x8 a1 = *(const bf16x8*)(Wb + ln * LHS + 32 + 8 * qd);
        f32x4 c[8] = {};
        #pragma unroll
        for (int nt = 0; nt < 8; nt++) {
            bf16x8 b0 = *(const bf16x8*)(W3t + (nt * 16 + ln) * 64 + 0 + 8 * qd);
            bf16x8 b1 = *(const bf16x8*)(W3t + (nt * 16 + ln) * 64 + 32 + 8 * qd);
            c[nt] = __builtin_amdgcn_mfma_f32_16x16x32_bf16(a0, b0, c[nt], 0, 0, 0);
            c[nt] = __builtin_amdgcn_mfma_f32_16x16x32_bf16(a1, b1, c[nt], 0, 0, 0);
        }
        #pragma unroll
        for (int nt = 0; nt < 8; nt++) {
            float bv = br3[r * DD + nt * 16 + ln];
            #pragma unroll
            for (int rg = 0; rg < 4; rg++) {
                float v = c[nt][rg] + bv;
                Wb[(qd * 4 + rg) * LXS + nt * 16 + ln] = (__bf16)fmaxf(v, 0.f);  // Ms
            }
        }
    }

    // ---- PROJ: contrib = msg @ Wn1_slice(1+r)  N64 K128 -> CSR slot (plain stores)
    {
        const __bf16* Wpt = wt + WPT_OFF + r * 8192;
        f32x4 c[4] = {};
        #pragma unroll
        for (int ks = 0; ks < 128; ks += 32) {
            bf16x8 a = *(const bf16x8*)(Wb + ln * LXS + ks + 8 * qd);
            #pragma unroll
            for (int nt = 0; nt < 4; nt++) {
                bf16x8 b = *(const bf16x8*)(Wpt + (nt * 16 + ln) * 128 + ks + 8 * qd);
                c[nt] = __builtin_amdgcn_mfma_f32_16x16x32_bf16(a, b, c[nt], 0, 0, 0);
            }
        }
        const int m0 = w << 4;
        #pragma unroll
        for (int rg = 0; rg < 4; rg++) {
            const int m = m0 + qd * 4 + rg;
            if (m < mcount) {
                const int sl = slotPerm[base + m];
                __bf16* cp = cbuf + (size_t)sl * HH;
                #pragma unroll
                for (int nt = 0; nt < 4; nt++)
                    cp[nt * 16 + ln] = (__bf16)c[nt][rg];
            }
        }
    }
}

// ---------------- node updater MLP (MFMA, barrier-free; CSR gather of contribs) ----------------
__global__ __launch_bounds__(NT, 8) void k_node(
    const float* __restrict__ nf,
    const float* __restrict__ bn1, const float* __restrict__ bn2, const float* __restrict__ bn3,
    const __bf16* __restrict__ wt, const __bf16* __restrict__ cbuf,
    const int* __restrict__ rowStart,
    float* __restrict__ out, int Nn)
{
    __shared__ __bf16 smem[SMEM_ELEMS];

    const int nb0 = blockIdx.x * BM;
    const int mcount = min(BM, Nn - nb0);
    const int tid = threadIdx.x;
    const int w = tid >> 6;
    const int lane = tid & 63;
    const int ln = lane & 15, qd = lane >> 4;
    const int m0 = w << 4;
    __bf16* Wb = smem + w * WBLK;

    // stage relu(node_feature) rows (wave-local)
    {
        const int m = tid >> 2, q = tid & 3;
        const int node = nb0 + ((m < mcount) ? m : 0);
        const float4* rp = (const float4*)(nf + (size_t)node * DD) + 8 * q;
        __bf16* xr = Wb + (m & 15) * LXS + 32 * q;
        #pragma unroll
        for (int jj = 0; jj < 4; jj++) {
            float4 v0 = rp[2 * jj], v1 = rp[2 * jj + 1];
            bf16x8 p;
            p[0] = (__bf16)fmaxf(v0.x, 0.f); p[1] = (__bf16)fmaxf(v0.y, 0.f);
            p[2] = (__bf16)fmaxf(v0.z, 0.f); p[3] = (__bf16)fmaxf(v0.w, 0.f);
            p[4] = (__bf16)fmaxf(v1.x, 0.f); p[5] = (__bf16)fmaxf(v1.y, 0.f);
            p[6] = (__bf16)fmaxf(v1.z, 0.f); p[7] = (__bf16)fmaxf(v1.w, 0.f);
            *(bf16x8*)(xr + 8 * jj) = p;
        }
    }

    // gather+sum CSR contribs: agg[rg][nt] (slots for consecutive nodes are contiguous)
    float agg[4][4] = {};
    #pragma unroll
    for (int rg = 0; rg < 4; rg++) {
        const int m = m0 + qd * 4 + rg;
        if (m < mcount) {
            const int node = nb0 + m;
            const int s0 = rowStart[node], s1 = rowStart[node + 1];
            for (int s = s0; s < s1; s++) {
                const __bf16* cp = cbuf + (size_t)s * HH + ln;
                agg[rg][0] += (float)cp[0];
                agg[rg][1] += (float)cp[16];
                agg[rg][2] += (float)cp[32];
                agg[rg][3] += (float)cp[48];
            }
        }
    }

    // GEMM1n: h = relu(relu(X) @ Wn1_0 + agg + bn1)  K128 N64
    {
        const __bf16* Wt = wt + WN1_OFF;
        f32x4 c[4] = {};
        #pragma unroll
        for (int ks = 0; ks < 128; ks += 32) {
            bf16x8 a = *(const bf16x8*)(Wb + ln * LXS + ks + 8 * qd);
            #pragma unroll
            for (int nt = 0; nt < 4; nt++) {
                bf16x8 b = *(const bf16x8*)(Wt + (nt * 16 + ln) * 128 + ks + 8 * qd);
                c[nt] = __builtin_amdgcn_mfma_f32_16x16x32_bf16(a, b, c[nt], 0, 0, 0);
            }
        }
        #pragma unroll
        for (int nt = 0; nt < 4; nt++) {
            float bv = bn1[nt * 16 + ln];
            #pragma unroll
            for (int rg = 0; rg < 4; rg++) {
                float v = c[nt][rg] + bv + agg[rg][nt];
                Wb[(qd * 4 + rg) * LHS + nt * 16 + ln] = (__bf16)fmaxf(v, 0.f);  // H1
            }
        }
    }

    // GEMM2n: K64 N64 (A preloaded; H2 overlays H1)
    {
        const __bf16* Wt = wt + WN2_OFF;
        bf16x8 a0 = *(const bf16x8*)(Wb + ln * LHS + 0 + 8 * qd);
        bf16x8 a1 = *(const bf16x8*)(Wb + ln * LHS + 32 + 8 * qd);
        f32x4 c[4] = {};
        #pragma unroll
        for (int nt = 0; nt < 4; nt++) {
            bf16x8 b0 = *(const bf16x8*)(Wt + (nt * 16 + ln) * 64 + 0 + 8 * qd);
            bf16x8 b1 = *(const bf16x8*)(Wt + (nt * 16 + ln) * 64 + 32 + 8 * qd);
            c[nt] = __builtin_amdgcn_mfma_f32_16x16x32_bf16(a0, b0, c[nt], 0, 0, 0);
            c[nt] = __builtin_amdgcn_mfma_f32_16x16x32_bf16(a1, b1, c[nt], 0, 0, 0);
        }
        #pragma unroll
        for (int nt = 0; nt < 4; nt++) {
            float bv = bn2[nt * 16 + ln];
            #pragma unroll
            for (int rg = 0; rg < 4; rg++) {
                float v = c[nt][rg] + bv;
                Wb[(qd * 4 + rg) * LHS + nt * 16 + ln] = (__bf16)fmaxf(v, 0.f);  // H2
            }
        }
    }

    // GEMM3n: K64 N128 -> out (+bn3, no relu)
    {
        const __bf16* Wt = wt + WN3_OFF;
        bf16x8 a0 = *(const bf16x8*)(Wb + ln * LHS + 0 + 8 * qd);
        bf16x8 a1 = *(const bf16x8*)(Wb + ln * LHS + 32 + 8 * qd);
        f32x4 c[8] = {};
        #pragma unroll
        for (int nt = 0; nt < 8; nt++) {
            bf16x8 b0 = *(const bf16x8*)(Wt + (nt * 16 + ln) * 64 + 0 + 8 * qd);
            bf16x8 b1 = *(const bf16x8*)(Wt + (nt * 16 + ln) * 64 + 32 + 8 * qd);
            c[nt] = __builtin_amdgcn_mfma_f32_16x16x32_bf16(a0, b0, c[nt], 0, 0, 0);
            c[nt] = __builtin_amdgcn_mfma_f32_16x16x32_bf16(a1, b1, c[nt], 0, 0, 0);
        }
        #pragma unroll
        for (int rg = 0; rg < 4; rg++) {
            const int m = m0 + qd * 4 + rg;
            if (m < mcount) {
                float* op = out + (size_t)(nb0 + m) * DD;
                #pragma unroll
                for (int nt = 0; nt < 8; nt++)
                    op[nt * 16 + ln] = c[nt][rg] + bn3[nt * 16 + ln];
            }
        }
    }
}

extern "C" void kernel_launch(void* const* d_in, const int* in_sizes, int n_in,
                              void* d_out, int out_size, void* d_ws, size_t ws_size,
                              hipStream_t stream) {
    const float* nf  = (const float*)d_in[0];
    const int*   es  = (const int*)d_in[1];
    const int*   ed  = (const int*)d_in[2];
    const int*   et  = (const int*)d_in[3];
    const float* Wr1 = (const float*)d_in[4];
    const float* br1 = (const float*)d_in[5];
    const float* Wr2 = (const float*)d_in[6];
    const float* br2 = (const float*)d_in[7];
    const float* Wr3 = (const float*)d_in[8];
    const float* br3 = (const float*)d_in[9];
    const float* Wn1 = (const float*)d_in[10];
    const float* bn1 = (const float*)d_in[11];
    const float* Wn2 = (const float*)d_in[12];
    const float* bn2 = (const float*)d_in[13];
    const float* Wn3 = (const float*)d_in[14];
    const float* bn3 = (const float*)d_in[15];
    float* out = (float*)d_out;

    const int Nn = in_sizes[0] / DD;   // 50000
    const int E  = in_sizes[1];        // 200000
    const int NB = (Nn + 1023) / 1024; // scan blocks (<=64)

    // workspace layout
    int* p = (int*)d_ws;
    int* cnt       = p;                 p += RR;      // ---- zero region start
    int* dstCnt    = p;                 p += Nn;      // ---- zero region end
    int* segSt     = p;                 p += RR;
    int* cursor    = p;                 p += RR;
    int* dstCursor = p;                 p += Nn;
    int* rowStart  = p;                 p += Nn + 1;
    int* blkSum    = p;                 p += 64;
    int* blkOff    = p;                 p += 64;
    int* esPerm    = p;                 p += E;
    int* slotPerm  = p;                 p += E;
    p += ((8 - ((p - (int*)d_ws) & 7)) & 7);          // 32B-align
    __bf16* wbf  = (__bf16*)p;          p += (WT_TOTAL + 1) / 2;
    __bf16* cbuf = (__bf16*)p;                         // E*HH bf16 = 25.6 MB

    hipMemsetAsync((void*)cnt, 0, (size_t)(RR + Nn) * sizeof(int), stream);

    const int nb = (E + NT - 1) / NT;
    k_hist <<<nb, NT, 0, stream>>>(et, ed, cnt, dstCnt, E);
    k_bsum <<<NB, 256, 0, stream>>>(dstCnt, blkSum, Nn);
    k_mid  <<<1, 64, 0, stream>>>(cnt, segSt, cursor, blkSum, blkOff, rowStart, NB, Nn, E);
    k_wout <<<NB, 256, 0, stream>>>(dstCnt, blkOff, rowStart, dstCursor, Nn);
    k_place<<<nb, NT, 0, stream>>>(et, ed, es, cursor, dstCursor, esPerm, slotPerm, E);
    k_prep <<<(WT_TOTAL + NT - 1) / NT, NT, 0, stream>>>(Wr1, Wr2, Wr3, Wn1, Wn2, Wn3, wbf);

    dim3 ge((E + BM - 1) / BM, RR);
    k_edge<<<ge, NT, 0, stream>>>(nf, br1, br2, br3, wbf, esPerm, slotPerm, segSt, cnt, cbuf);
    k_node<<<(Nn + BM - 1) / BM, NT, 0, stream>>>(nf, bn1, bn2, bn3, wbf, cbuf, rowStart, out, Nn);
}

// Round 5
// 279.290 us; speedup vs baseline: 1.3559x; 1.0465x over previous
//
#include <hip/hip_runtime.h>

#define DD 128
#define HH 64
#define RR 4
#define NT 256

typedef __attribute__((ext_vector_type(8))) __bf16 bf16x8;
typedef __attribute__((ext_vector_type(4))) float f32x4;

// per-wave LDS blocks (bf16 elements), padded rows (+8) to rotate banks
#define LXS 136   // X / Msg row stride (128 + 8)
#define LHS 72    // H row stride (64 + 8)
// k_dense: Xs[16][136] | H[16][72] (H1/H2 overlay) | Ms[16][136]
#define DW_XS 0
#define DW_H  2176
#define DW_MS 3328
#define DWBLK 5504
#define DSMEM (4 * DWBLK)    // 44032 B -> 3 blocks/CU
// k_node: Xs[16][136] | H[16][72]
#define NWBLK 3328
#define NSMEM (2 * NWBLK)    // 13312 B, 128-thr blocks -> 12 blocks/CU

// transposed bf16 weight pool offsets (elements)
#define W1T_OFF 0        // [R][64][128]
#define W2T_OFF 32768    // [R][64][64]
#define W3T_OFF 49152    // [R][128][64]
#define WPT_OFF 81920    // [R][64][128]  (Wn1 slice 1+r)
#define WN1_OFF 114688   // [64][128]     (Wn1 slice 0)
#define WN2_OFF 122880   // [64][64]
#define WN3_OFF 126976   // [128][64]
#define WT_TOTAL 135168

// ---------------- dst histogram ----------------
__global__ void k_hist(const int* __restrict__ ed, int* __restrict__ dstCnt, int E) {
    int i = blockIdx.x * blockDim.x + threadIdx.x;
    if (i < E) atomicAdd(&dstCnt[ed[i]], 1);
}

// ---------------- parallel CSR scan ----------------
__global__ void k_bsum(const int* __restrict__ dstCnt, int* __restrict__ blkSum, int Nn) {
    int b = blockIdx.x, t = threadIdx.x;
    int g = b * 1024 + t * 4;
    int s = 0;
    if (g + 3 < Nn) { int4 v = *(const int4*)(dstCnt + g); s = v.x + v.y + v.z + v.w; }
    else { for (int k = 0; k < 4; k++) if (g + k < Nn) s += dstCnt[g + k]; }
    for (int off = 32; off > 0; off >>= 1) s += __shfl_down(s, off);
    __shared__ int ws[4];
    if ((t & 63) == 0) ws[t >> 6] = s;
    __syncthreads();
    if (t == 0) blkSum[b] = ws[0] + ws[1] + ws[2] + ws[3];
}

__global__ void k_mid(const int* __restrict__ blkSum, int* __restrict__ blkOff,
                      int* __restrict__ rowStart, int NB, int Nn, int E) {
    int lane = threadIdx.x;
    int s = (lane < NB) ? blkSum[lane] : 0;
    int sc = s;
    #pragma unroll
    for (int off = 1; off < 64; off <<= 1) { int u = __shfl_up(sc, off); if (lane >= off) sc += u; }
    if (lane < NB) blkOff[lane] = sc - s;
    if (lane == 0) rowStart[Nn] = E;
}

__global__ void k_wout(const int* __restrict__ dstCnt, const int* __restrict__ blkOff,
                       int* __restrict__ rowStart, int* __restrict__ dstCursor, int Nn) {
    int b = blockIdx.x, t = threadIdx.x;
    int g = b * 1024 + t * 4;
    int4 v = {0, 0, 0, 0};
    bool full = (g + 3 < Nn);
    if (full) v = *(const int4*)(dstCnt + g);
    else {
        if (g     < Nn) v.x = dstCnt[g];
        if (g + 1 < Nn) v.y = dstCnt[g + 1];
        if (g + 2 < Nn) v.z = dstCnt[g + 2];
    }
    int s = v.x + v.y + v.z + v.w;
    int lane = t & 63, wv = t >> 6;
    int sc = s;
    #pragma unroll
    for (int off = 1; off < 64; off <<= 1) { int u = __shfl_up(sc, off); if (lane >= off) sc += u; }
    __shared__ int wsum[4];
    if (lane == 63) wsum[wv] = sc;
    __syncthreads();
    int wadd = 0;
    for (int i = 0; i < wv; i++) wadd += wsum[i];
    int e0 = blkOff[b] + wadd + sc - s;
    int4 rs; rs.x = e0; rs.y = e0 + v.x; rs.z = rs.y + v.y; rs.w = rs.z + v.z;
    if (full) { *(int4*)(rowStart + g) = rs; *(int4*)(dstCursor + g) = rs; }
    else {
        int a[4] = {rs.x, rs.y, rs.z, rs.w};
        for (int k = 0; k < 4; k++) if (g + k < Nn) { rowStart[g + k] = a[k]; dstCursor[g + k] = a[k]; }
    }
}

// ---------------- CSR fill: per edge store packed (type*Nn + src) key ----------------
__global__ void k_place(const int* __restrict__ et, const int* __restrict__ ed,
                        const int* __restrict__ es, int* __restrict__ dstCursor,
                        int* __restrict__ csrKey, int E, int Nn) {
    int i = blockIdx.x * blockDim.x + threadIdx.x;
    if (i < E) {
        int sl = atomicAdd(&dstCursor[ed[i]], 1);
        csrKey[sl] = et[i] * Nn + es[i];
    }
}

// ---------------- weight transpose+convert ----------------
__global__ void k_prep(const float* __restrict__ Wr1, const float* __restrict__ Wr2,
                       const float* __restrict__ Wr3, const float* __restrict__ Wn1,
                       const float* __restrict__ Wn2, const float* __restrict__ Wn3,
                       __bf16* __restrict__ wt) {
    int i = blockIdx.x * blockDim.x + threadIdx.x;
    float v;
    if (i < 32768) {                       // W1t [r][n64][k128]
        int r = i >> 13, n = (i >> 7) & 63, k = i & 127;
        v = Wr1[r * 8192 + k * 64 + n];
    } else if (i < 49152) {                // W2t [r][n64][k64]
        int j = i - 32768; int r = j >> 12, n = (j >> 6) & 63, k = j & 63;
        v = Wr2[r * 4096 + k * 64 + n];
    } else if (i < 81920) {                // W3t [r][n128][k64]
        int j = i - 49152; int r = j >> 13, n = (j >> 6) & 127, k = j & 63;
        v = Wr3[r * 8192 + k * 128 + n];
    } else if (i < 114688) {               // Wpt [r][n64][k128]
        int j = i - 81920; int r = j >> 13, n = (j >> 7) & 63, k = j & 127;
        v = Wn1[((1 + r) * 128 + k) * 64 + n];
    } else if (i < 122880) {               // Wn1t0 [n64][k128]
        int j = i - 114688; int n = j >> 7, k = j & 127;
        v = Wn1[k * 64 + n];
    } else if (i < 126976) {               // Wn2t [n64][k64]
        int j = i - 122880; int n = j >> 6, k = j & 63;
        v = Wn2[k * 64 + n];
    } else if (i < WT_TOTAL) {             // Wn3t [n128][k64]
        int j = i - 126976; int n = j >> 6, k = j & 63;
        v = Wn3[k * 128 + n];
    } else return;
    wt[i] = (__bf16)v;
}

// ---------------- dense per-(relation,node) message+projection pipeline ----------------
// Block: 64 consecutive nodes, 4 waves (16 rows each). For r=0..3:
//   h1=relu(X W1+b1); h2=relu(h1 W2+b2); msg=relu(h2 W3+b3); contrib=msg Wpt_r
//   -> contribAll[(r*Nn+node)*64] bf16 (coalesced-ish stores, no gather anywhere)
__global__ __launch_bounds__(NT, 3) void k_dense(
    const float* __restrict__ nf,
    const float* __restrict__ br1, const float* __restrict__ br2, const float* __restrict__ br3,
    const __bf16* __restrict__ wt, __bf16* __restrict__ ca, int Nn)
{
    __shared__ __bf16 smem[DSMEM];
    const int nb0 = blockIdx.x * 64;
    const int tid = threadIdx.x;
    const int w = tid >> 6;
    const int lane = tid & 63;
    const int ln = lane & 15, qd = lane >> 4;
    const int m0 = w << 4;
    __bf16* Xs = smem + w * DWBLK + DW_XS;
    __bf16* Hs = smem + w * DWBLK + DW_H;
    __bf16* Ms = smem + w * DWBLK + DW_MS;

    // ---- stage X rows (coalesced: consecutive nodes)
    {
        const int m = tid >> 2, q = tid & 3;
        const int node = min(nb0 + m, Nn - 1);
        const float4* rp = (const float4*)(nf + (size_t)node * DD) + 8 * q;
        __bf16* xr = Xs + (m & 15) * LXS + 32 * q;
        #pragma unroll
        for (int jj = 0; jj < 4; jj++) {
            float4 v0 = rp[2 * jj], v1 = rp[2 * jj + 1];
            bf16x8 p;
            p[0] = (__bf16)v0.x; p[1] = (__bf16)v0.y; p[2] = (__bf16)v0.z; p[3] = (__bf16)v0.w;
            p[4] = (__bf16)v1.x; p[5] = (__bf16)v1.y; p[6] = (__bf16)v1.z; p[7] = (__bf16)v1.w;
            *(bf16x8*)(xr + 8 * jj) = p;
        }
    }

    for (int r = 0; r < RR; r++) {
        // GEMM1: K=128 N=64 (A from Xs — preserved across relations)
        {
            const __bf16* W1t = wt + W1T_OFF + r * 8192;
            f32x4 c[4] = {};
            #pragma unroll
            for (int ks = 0; ks < 128; ks += 32) {
                bf16x8 a = *(const bf16x8*)(Xs + ln * LXS + ks + 8 * qd);
                #pragma unroll
                for (int nt = 0; nt < 4; nt++) {
                    bf16x8 b = *(const bf16x8*)(W1t + (nt * 16 + ln) * 128 + ks + 8 * qd);
                    c[nt] = __builtin_amdgcn_mfma_f32_16x16x32_bf16(a, b, c[nt], 0, 0, 0);
                }
            }
            #pragma unroll
            for (int nt = 0; nt < 4; nt++) {
                float bv = br1[r * HH + nt * 16 + ln];
                #pragma unroll
                for (int rg = 0; rg < 4; rg++) {
                    float v = c[nt][rg] + bv;
                    Hs[(qd * 4 + rg) * LHS + nt * 16 + ln] = (__bf16)fmaxf(v, 0.f);  // H1
                }
            }
        }
        // GEMM2: K=64 (A preloaded; H2 overlays H1)
        {
            const __bf16* W2t = wt + W2T_OFF + r * 4096;
            bf16x8 a0 = *(const bf16x8*)(Hs + ln * LHS + 0 + 8 * qd);
            bf16x8 a1 = *(const bf16x8*)(Hs + ln * LHS + 32 + 8 * qd);
            f32x4 c[4] = {};
            #pragma unroll
            for (int nt = 0; nt < 4; nt++) {
                bf16x8 b0 = *(const bf16x8*)(W2t + (nt * 16 + ln) * 64 + 0 + 8 * qd);
                bf16x8 b1 = *(const bf16x8*)(W2t + (nt * 16 + ln) * 64 + 32 + 8 * qd);
                c[nt] = __builtin_amdgcn_mfma_f32_16x16x32_bf16(a0, b0, c[nt], 0, 0, 0);
                c[nt] = __builtin_amdgcn_mfma_f32_16x16x32_bf16(a1, b1, c[nt], 0, 0, 0);
            }
            #pragma unroll
            for (int nt = 0; nt < 4; nt++) {
                float bv = br2[r * HH + nt * 16 + ln];
                #pragma unroll
                for (int rg = 0; rg < 4; rg++) {
                    float v = c[nt][rg] + bv;
                    Hs[(qd * 4 + rg) * LHS + nt * 16 + ln] = (__bf16)fmaxf(v, 0.f);  // H2
                }
            }
        }
        // GEMM3: N=128 K=64 -> Ms
        {
            const __bf16* W3t = wt + W3T_OFF + r * 8192;
            bf16x8 a0 = *(const bf16x8*)(Hs + ln * LHS + 0 + 8 * qd);
            bf16x8 a1 = *(const bf16x8*)(Hs + ln * LHS + 32 + 8 * qd);
            f32x4 c[8] = {};
            #pragma unroll
            for (int nt = 0; nt < 8; nt++) {
                bf16x8 b0 = *(const bf16x8*)(W3t + (nt * 16 + ln) * 64 + 0 + 8 * qd);
                bf16x8 b1 = *(const bf16x8*)(W3t + (nt * 16 + ln) * 64 + 32 + 8 * qd);
                c[nt] = __builtin_amdgcn_mfma_f32_16x16x32_bf16(a0, b0, c[nt], 0, 0, 0);
                c[nt] = __builtin_amdgcn_mfma_f32_16x16x32_bf16(a1, b1, c[nt], 0, 0, 0);
            }
            #pragma unroll
            for (int nt = 0; nt < 8; nt++) {
                float bv = br3[r * DD + nt * 16 + ln];
                #pragma unroll
                for (int rg = 0; rg < 4; rg++) {
                    float v = c[nt][rg] + bv;
                    Ms[(qd * 4 + rg) * LXS + nt * 16 + ln] = (__bf16)fmaxf(v, 0.f);
                }
            }
        }
        // PROJ: K=128 N=64 -> contribAll rows (plain bf16 stores)
        {
            const __bf16* Wpt = wt + WPT_OFF + r * 8192;
            f32x4 c[4] = {};
            #pragma unroll
            for (int ks = 0; ks < 128; ks += 32) {
                bf16x8 a = *(const bf16x8*)(Ms + ln * LXS + ks + 8 * qd);
                #pragma unroll
                for (int nt = 0; nt < 4; nt++) {
                    bf16x8 b = *(const bf16x8*)(Wpt + (nt * 16 + ln) * 128 + ks + 8 * qd);
                    c[nt] = __builtin_amdgcn_mfma_f32_16x16x32_bf16(a, b, c[nt], 0, 0, 0);
                }
            }
            #pragma unroll
            for (int rg = 0; rg < 4; rg++) {
                const int node = nb0 + m0 + qd * 4 + rg;
                if (node < Nn) {
                    __bf16* cp = ca + ((size_t)r * Nn + node) * HH;
                    #pragma unroll
                    for (int nt = 0; nt < 4; nt++)
                        cp[nt * 16 + ln] = (__bf16)c[nt][rg];
                }
            }
        }
    }
}

// ---------------- node updater MLP (128-thr blocks; CSR gather of dense contribs) ----------------
__global__ __launch_bounds__(128, 6) void k_node(
    const float* __restrict__ nf,
    const float* __restrict__ bn1, const float* __restrict__ bn2, const float* __restrict__ bn3,
    const __bf16* __restrict__ wt, const __bf16* __restrict__ ca,
    const int* __restrict__ rowStart, const int* __restrict__ csrKey,
    float* __restrict__ out, int Nn)
{
    __shared__ __bf16 smem[NSMEM];
    const int nb0 = blockIdx.x * 32;
    const int tid = threadIdx.x;
    const int w = tid >> 6;
    const int lane = tid & 63;
    const int ln = lane & 15, qd = lane >> 4;
    const int m0 = w << 4;
    __bf16* Xs = smem + w * NWBLK;
    __bf16* Hs = smem + w * NWBLK + 2176;

    // stage relu(node_feature) rows (coalesced)
    {
        const int m = tid >> 2, q = tid & 3;
        const int node = min(nb0 + m, Nn - 1);
        const float4* rp = (const float4*)(nf + (size_t)node * DD) + 8 * q;
        __bf16* xr = Xs + (m & 15) * LXS + 32 * q;
        #pragma unroll
        for (int jj = 0; jj < 4; jj++) {
            float4 v0 = rp[2 * jj], v1 = rp[2 * jj + 1];
            bf16x8 p;
            p[0] = (__bf16)fmaxf(v0.x, 0.f); p[1] = (__bf16)fmaxf(v0.y, 0.f);
            p[2] = (__bf16)fmaxf(v0.z, 0.f); p[3] = (__bf16)fmaxf(v0.w, 0.f);
            p[4] = (__bf16)fmaxf(v1.x, 0.f); p[5] = (__bf16)fmaxf(v1.y, 0.f);
            p[6] = (__bf16)fmaxf(v1.z, 0.f); p[7] = (__bf16)fmaxf(v1.w, 0.f);
            *(bf16x8*)(xr + 8 * jj) = p;
        }
    }

    // gather+sum contribs via CSR: 4 independent chains (rg unrolled) per wave
    float agg[4][4] = {};
    #pragma unroll
    for (int rg = 0; rg < 4; rg++) {
        const int m = m0 + qd * 4 + rg;
        const int node = nb0 + m;
        if (node < Nn) {
            const int s0 = rowStart[node], s1 = rowStart[node + 1];
            for (int s = s0; s < s1; s++) {
                const int key = csrKey[s];
                const __bf16* cp = ca + (size_t)key * HH + ln;
                agg[rg][0] += (float)cp[0];
                agg[rg][1] += (float)cp[16];
                agg[rg][2] += (float)cp[32];
                agg[rg][3] += (float)cp[48];
            }
        }
    }

    // GEMM1n: relu(relu(X) @ Wn1_0 + agg + bn1)  K=128 N=64
    {
        const __bf16* Wt = wt + WN1_OFF;
        f32x4 c[4] = {};
        #pragma unroll
        for (int ks = 0; ks < 128; ks += 32) {
            bf16x8 a = *(const bf16x8*)(Xs + ln * LXS + ks + 8 * qd);
            #pragma unroll
            for (int nt = 0; nt < 4; nt++) {
                bf16x8 b = *(const bf16x8*)(Wt + (nt * 16 + ln) * 128 + ks + 8 * qd);
                c[nt] = __builtin_amdgcn_mfma_f32_16x16x32_bf16(a, b, c[nt], 0, 0, 0);
            }
        }
        #pragma unroll
        for (int nt = 0; nt < 4; nt++) {
            float bv = bn1[nt * 16 + ln];
            #pragma unroll
            for (int rg = 0; rg < 4; rg++) {
                float v = c[nt][rg] + bv + agg[rg][nt];
                Hs[(qd * 4 + rg) * LHS + nt * 16 + ln] = (__bf16)fmaxf(v, 0.f);  // H1
            }
        }
    }

    // GEMM2n: K=64 (A preloaded; H2 overlays H1)
    {
        const __bf16* Wt = wt + WN2_OFF;
        bf16x8 a0 = *(const bf16x8*)(Hs + ln * LHS + 0 + 8 * qd);
        bf16x8 a1 = *(const bf16x8*)(Hs + ln * LHS + 32 + 8 * qd);
        f32x4 c[4] = {};
        #pragma unroll
        for (int nt = 0; nt < 4; nt++) {
            bf16x8 b0 = *(const bf16x8*)(Wt + (nt * 16 + ln) * 64 + 0 + 8 * qd);
            bf16x8 b1 = *(const bf16x8*)(Wt + (nt * 16 + ln) * 64 + 32 + 8 * qd);
            c[nt] = __builtin_amdgcn_mfma_f32_16x16x32_bf16(a0, b0, c[nt], 0, 0, 0);
            c[nt] = __builtin_amdgcn_mfma_f32_16x16x32_bf16(a1, b1, c[nt], 0, 0, 0);
        }
        #pragma unroll
        for (int nt = 0; nt < 4; nt++) {
            float bv = bn2[nt * 16 + ln];
            #pragma unroll
            for (int rg = 0; rg < 4; rg++) {
                float v = c[nt][rg] + bv;
                Hs[(qd * 4 + rg) * LHS + nt * 16 + ln] = (__bf16)fmaxf(v, 0.f);  // H2
            }
        }
    }

    // GEMM3n: K=64 N=128 -> out
    {
        const __bf16* Wt = wt + WN3_OFF;
        bf16x8 a0 = *(const bf16x8*)(Hs + ln * LHS + 0 + 8 * qd);
        bf16x8 a1 = *(const bf16x8*)(Hs + ln * LHS + 32 + 8 * qd);
        f32x4 c[8] = {};
        #pragma unroll
        for (int nt = 0; nt < 8; nt++) {
            bf16x8 b0 = *(const bf16x8*)(Wt + (nt * 16 + ln) * 64 + 0 + 8 * qd);
            bf16x8 b1 = *(const bf16x8*)(Wt + (nt * 16 + ln) * 64 + 32 + 8 * qd);
            c[nt] = __builtin_amdgcn_mfma_f32_16x16x32_bf16(a0, b0, c[nt], 0, 0, 0);
            c[nt] = __builtin_amdgcn_mfma_f32_16x16x32_bf16(a1, b1, c[nt], 0, 0, 0);
        }
        #pragma unroll
        for (int rg = 0; rg < 4; rg++) {
            const int node = nb0 + m0 + qd * 4 + rg;
            if (node < Nn) {
                float* op = out + (size_t)node * DD;
                #pragma unroll
                for (int nt = 0; nt < 8; nt++)
                    op[nt * 16 + ln] = c[nt][rg] + bn3[nt * 16 + ln];
            }
        }
    }
}

extern "C" void kernel_launch(void* const* d_in, const int* in_sizes, int n_in,
                              void* d_out, int out_size, void* d_ws, size_t ws_size,
                              hipStream_t stream) {
    const float* nf  = (const float*)d_in[0];
    const int*   es  = (const int*)d_in[1];
    const int*   ed  = (const int*)d_in[2];
    const int*   et  = (const int*)d_in[3];
    const float* Wr1 = (const float*)d_in[4];
    const float* br1 = (const float*)d_in[5];
    const float* Wr2 = (const float*)d_in[6];
    const float* br2 = (const float*)d_in[7];
    const float* Wr3 = (const float*)d_in[8];
    const float* br3 = (const float*)d_in[9];
    const float* Wn1 = (const float*)d_in[10];
    const float* bn1 = (const float*)d_in[11];
    const float* Wn2 = (const float*)d_in[12];
    const float* bn2 = (const float*)d_in[13];
    const float* Wn3 = (const float*)d_in[14];
    const float* bn3 = (const float*)d_in[15];
    float* out = (float*)d_out;

    const int Nn = in_sizes[0] / DD;   // 50000
    const int E  = in_sizes[1];        // 200000
    const int NB = (Nn + 1023) / 1024; // <=64

    // workspace layout
    int* p = (int*)d_ws;
    int* dstCnt    = p;                 p += Nn;      // zeroed
    int* dstCursor = p;                 p += Nn;
    int* rowStart  = p;                 p += Nn + 1;
    int* blkSum    = p;                 p += 64;
    int* blkOff    = p;                 p += 64;
    int* csrKey    = p;                 p += E;
    p += ((8 - ((p - (int*)d_ws) & 7)) & 7);          // 32B-align
    __bf16* wbf = (__bf16*)p;           p += (WT_TOTAL + 1) / 2;
    __bf16* ca  = (__bf16*)p;                          // RR*Nn*HH bf16 = 25.6 MB

    hipMemsetAsync((void*)dstCnt, 0, (size_t)Nn * sizeof(int), stream);

    const int nb = (E + NT - 1) / NT;
    k_hist <<<nb, NT, 0, stream>>>(ed, dstCnt, E);
    k_bsum <<<NB, 256, 0, stream>>>(dstCnt, blkSum, Nn);
    k_mid  <<<1, 64, 0, stream>>>(blkSum, blkOff, rowStart, NB, Nn, E);
    k_wout <<<NB, 256, 0, stream>>>(dstCnt, blkOff, rowStart, dstCursor, Nn);
    k_place<<<nb, NT, 0, stream>>>(et, ed, es, dstCursor, csrKey, E, Nn);
    k_prep <<<(WT_TOTAL + NT - 1) / NT, NT, 0, stream>>>(Wr1, Wr2, Wr3, Wn1, Wn2, Wn3, wbf);

    k_dense<<<(Nn + 63) / 64, NT, 0, stream>>>(nf, br1, br2, br3, wbf, ca, Nn);
    k_node <<<(Nn + 31) / 32, 128, 0, stream>>>(nf, bn1, bn2, bn3, wbf, ca, rowStart, csrKey, out, Nn);
}

// Round 6
// 276.944 us; speedup vs baseline: 1.3674x; 1.0085x over previous
//
#include <hip/hip_runtime.h>

#define DD 128
#define HH 64
#define RR 4
#define NT 256

typedef __attribute__((ext_vector_type(8))) __bf16 bf16x8;
typedef __attribute__((ext_vector_type(4))) float f32x4;

// per-wave LDS (bf16 elements): Xs[16][136] (overlaid by Ms after A-frags cached
// in regs) + H[16][72] (H1/H2 overlay). Wave-local, barrier-free (DS in-order).
#define LXS 136
#define LHS 72
#define WBLK 3328          // 2176 (Xs/Ms) + 1152 (H)
#define DSMEM (4 * WBLK)   // 26624 B -> LDS allows 6 blocks/CU (VGPR caps at 4)
#define NSMEM (2 * WBLK)   // k_node: 2 waves

// transposed bf16 weight pool offsets (elements)
#define W1T_OFF 0        // [R][64][128]
#define W2T_OFF 32768    // [R][64][64]
#define W3T_OFF 49152    // [R][128][64]
#define WPT_OFF 81920    // [R][64][128]  (Wn1 slice 1+r)
#define WN1_OFF 114688   // [64][128]     (Wn1 slice 0)
#define WN2_OFF 122880   // [64][64]
#define WN3_OFF 126976   // [128][64]
#define WT_TOTAL 135168

#define MFMA(a, b, c) __builtin_amdgcn_mfma_f32_16x16x32_bf16(a, b, c, 0, 0, 0)

// ---------------- dst histogram ----------------
__global__ void k_hist(const int* __restrict__ ed, int* __restrict__ dstCnt, int E) {
    int i = blockIdx.x * blockDim.x + threadIdx.x;
    if (i < E) atomicAdd(&dstCnt[ed[i]], 1);
}

// ---------------- parallel CSR scan ----------------
__global__ void k_bsum(const int* __restrict__ dstCnt, int* __restrict__ blkSum, int Nn) {
    int b = blockIdx.x, t = threadIdx.x;
    int g = b * 1024 + t * 4;
    int s = 0;
    if (g + 3 < Nn) { int4 v = *(const int4*)(dstCnt + g); s = v.x + v.y + v.z + v.w; }
    else { for (int k = 0; k < 4; k++) if (g + k < Nn) s += dstCnt[g + k]; }
    for (int off = 32; off > 0; off >>= 1) s += __shfl_down(s, off);
    __shared__ int ws[4];
    if ((t & 63) == 0) ws[t >> 6] = s;
    __syncthreads();
    if (t == 0) blkSum[b] = ws[0] + ws[1] + ws[2] + ws[3];
}

__global__ void k_mid(const int* __restrict__ blkSum, int* __restrict__ blkOff,
                      int* __restrict__ rowStart, int NB, int Nn, int E) {
    int lane = threadIdx.x;
    int s = (lane < NB) ? blkSum[lane] : 0;
    int sc = s;
    #pragma unroll
    for (int off = 1; off < 64; off <<= 1) { int u = __shfl_up(sc, off); if (lane >= off) sc += u; }
    if (lane < NB) blkOff[lane] = sc - s;
    if (lane == 0) rowStart[Nn] = E;
}

__global__ void k_wout(const int* __restrict__ dstCnt, const int* __restrict__ blkOff,
                       int* __restrict__ rowStart, int* __restrict__ dstCursor, int Nn) {
    int b = blockIdx.x, t = threadIdx.x;
    int g = b * 1024 + t * 4;
    int4 v = {0, 0, 0, 0};
    bool full = (g + 3 < Nn);
    if (full) v = *(const int4*)(dstCnt + g);
    else {
        if (g     < Nn) v.x = dstCnt[g];
        if (g + 1 < Nn) v.y = dstCnt[g + 1];
        if (g + 2 < Nn) v.z = dstCnt[g + 2];
    }
    int s = v.x + v.y + v.z + v.w;
    int lane = t & 63, wv = t >> 6;
    int sc = s;
    #pragma unroll
    for (int off = 1; off < 64; off <<= 1) { int u = __shfl_up(sc, off); if (lane >= off) sc += u; }
    __shared__ int wsum[4];
    if (lane == 63) wsum[wv] = sc;
    __syncthreads();
    int wadd = 0;
    for (int i = 0; i < wv; i++) wadd += wsum[i];
    int e0 = blkOff[b] + wadd + sc - s;
    int4 rs; rs.x = e0; rs.y = e0 + v.x; rs.z = rs.y + v.y; rs.w = rs.z + v.z;
    if (full) { *(int4*)(rowStart + g) = rs; *(int4*)(dstCursor + g) = rs; }
    else {
        int a[4] = {rs.x, rs.y, rs.z, rs.w};
        for (int k = 0; k < 4; k++) if (g + k < Nn) { rowStart[g + k] = a[k]; dstCursor[g + k] = a[k]; }
    }
}

// ---------------- CSR fill: per edge store packed (type*Nn + src) key ----------------
__global__ void k_place(const int* __restrict__ et, const int* __restrict__ ed,
                        const int* __restrict__ es, int* __restrict__ dstCursor,
                        int* __restrict__ csrKey, int E, int Nn) {
    int i = blockIdx.x * blockDim.x + threadIdx.x;
    if (i < E) {
        int sl = atomicAdd(&dstCursor[ed[i]], 1);
        csrKey[sl] = et[i] * Nn + es[i];
    }
}

// ---------------- weight transpose+convert ----------------
__global__ void k_prep(const float* __restrict__ Wr1, const float* __restrict__ Wr2,
                       const float* __restrict__ Wr3, const float* __restrict__ Wn1,
                       const float* __restrict__ Wn2, const float* __restrict__ Wn3,
                       __bf16* __restrict__ wt) {
    int i = blockIdx.x * blockDim.x + threadIdx.x;
    float v;
    if (i < 32768) {                       // W1t [r][n64][k128]
        int r = i >> 13, n = (i >> 7) & 63, k = i & 127;
        v = Wr1[r * 8192 + k * 64 + n];
    } else if (i < 49152) {                // W2t [r][n64][k64]
        int j = i - 32768; int r = j >> 12, n = (j >> 6) & 63, k = j & 63;
        v = Wr2[r * 4096 + k * 64 + n];
    } else if (i < 81920) {                // W3t [r][n128][k64]
        int j = i - 49152; int r = j >> 13, n = (j >> 6) & 127, k = j & 63;
        v = Wr3[r * 8192 + k * 128 + n];
    } else if (i < 114688) {               // Wpt [r][n64][k128]
        int j = i - 81920; int r = j >> 13, n = (j >> 7) & 63, k = j & 127;
        v = Wn1[((1 + r) * 128 + k) * 64 + n];
    } else if (i < 122880) {               // Wn1t0 [n64][k128]
        int j = i - 114688; int n = j >> 7, k = j & 127;
        v = Wn1[k * 64 + n];
    } else if (i < 126976) {               // Wn2t [n64][k64]
        int j = i - 122880; int n = j >> 6, k = j & 63;
        v = Wn2[k * 64 + n];
    } else if (i < WT_TOTAL) {             // Wn3t [n128][k64]
        int j = i - 126976; int n = j >> 6, k = j & 63;
        v = Wn3[k * 128 + n];
    } else return;
    wt[i] = (__bf16)v;
}

// ---------------- dense per-(relation,node) message+projection pipeline ----------------
// Per wave: 16 nodes. X A-frags cached in regs; per relation r:
//   GEMM1 (regs->H1) -> GEMM2 (H1->H2 overlay) -> GEMM3 (H2->Ms) -> PROJ (Ms->ca)
// All B-fragment loads hoisted 8-wide for outstanding-load ILP.
__global__ __launch_bounds__(NT, 4) void k_dense(
    const float* __restrict__ nf,
    const float* __restrict__ br1, const float* __restrict__ br2, const float* __restrict__ br3,
    const __bf16* __restrict__ wt, __bf16* __restrict__ ca, int Nn)
{
    __shared__ __bf16 smem[DSMEM];
    const int nb0 = blockIdx.x * 64;
    const int tid = threadIdx.x;
    const int w = tid >> 6;
    const int lane = tid & 63;
    const int ln = lane & 15, qd = lane >> 4;
    const int m0 = w << 4;
    __bf16* Xs = smem + w * WBLK;          // staging; becomes Ms after ax cached
    __bf16* Hs = smem + w * WBLK + 2176;
    __bf16* Ms = Xs;

    // ---- stage X rows (coalesced)
    {
        const int m = tid >> 2, q = tid & 3;
        const int node = min(nb0 + m, Nn - 1);
        const float4* rp = (const float4*)(nf + (size_t)node * DD) + 8 * q;
        __bf16* xr = Xs + (m & 15) * LXS + 32 * q;
        #pragma unroll
        for (int jj = 0; jj < 4; jj++) {
            float4 v0 = rp[2 * jj], v1 = rp[2 * jj + 1];
            bf16x8 p;
            p[0] = (__bf16)v0.x; p[1] = (__bf16)v0.y; p[2] = (__bf16)v0.z; p[3] = (__bf16)v0.w;
            p[4] = (__bf16)v1.x; p[5] = (__bf16)v1.y; p[6] = (__bf16)v1.z; p[7] = (__bf16)v1.w;
            *(bf16x8*)(xr + 8 * jj) = p;
        }
    }

    // ---- cache X A-frags in regs (Xs dead afterwards; Ms may overlay)
    bf16x8 ax[4];
    #pragma unroll
    for (int i = 0; i < 4; i++)
        ax[i] = *(const bf16x8*)(Xs + ln * LXS + i * 32 + 8 * qd);

    for (int r = 0; r < RR; r++) {
        // ---- GEMM1: h1 = relu(X W1 + b1)  K=128 N=64
        {
            const __bf16* W1t = wt + W1T_OFF + r * 8192;
            f32x4 c[4] = {};
            #pragma unroll
            for (int g = 0; g < 2; g++) {          // ks4 groups {0,1},{2,3}
                bf16x8 b[8];
                #pragma unroll
                for (int i = 0; i < 8; i++) {
                    const int nt = i & 3, ks4 = g * 2 + (i >> 2);
                    b[i] = *(const bf16x8*)(W1t + (nt * 16 + ln) * 128 + ks4 * 32 + 8 * qd);
                }
                #pragma unroll
                for (int k2 = 0; k2 < 2; k2++)
                    #pragma unroll
                    for (int nt = 0; nt < 4; nt++)
                        c[nt] = MFMA(ax[g * 2 + k2], b[k2 * 4 + nt], c[nt]);
            }
            #pragma unroll
            for (int nt = 0; nt < 4; nt++) {
                float bv = br1[r * HH + nt * 16 + ln];
                #pragma unroll
                for (int rg = 0; rg < 4; rg++) {
                    float v = c[nt][rg] + bv;
                    Hs[(qd * 4 + rg) * LHS + nt * 16 + ln] = (__bf16)fmaxf(v, 0.f);
                }
            }
        }
        // ---- GEMM2: h2 = relu(h1 W2 + b2)  K=64 (H2 overlays H1)
        {
            const __bf16* W2t = wt + W2T_OFF + r * 4096;
            bf16x8 a0 = *(const bf16x8*)(Hs + ln * LHS + 0 + 8 * qd);
            bf16x8 a1 = *(const bf16x8*)(Hs + ln * LHS + 32 + 8 * qd);
            bf16x8 b[8];
            #pragma unroll
            for (int i = 0; i < 8; i++) {
                const int nt = i & 3, ks2 = i >> 2;
                b[i] = *(const bf16x8*)(W2t + (nt * 16 + ln) * 64 + ks2 * 32 + 8 * qd);
            }
            f32x4 c[4] = {};
            #pragma unroll
            for (int nt = 0; nt < 4; nt++) {
                c[nt] = MFMA(a0, b[nt], c[nt]);
                c[nt] = MFMA(a1, b[4 + nt], c[nt]);
            }
            #pragma unroll
            for (int nt = 0; nt < 4; nt++) {
                float bv = br2[r * HH + nt * 16 + ln];
                #pragma unroll
                for (int rg = 0; rg < 4; rg++) {
                    float v = c[nt][rg] + bv;
                    Hs[(qd * 4 + rg) * LHS + nt * 16 + ln] = (__bf16)fmaxf(v, 0.f);
                }
            }
        }
        // ---- GEMM3: msg = relu(h2 W3 + b3)  N=128 K=64 -> Ms
        {
            const __bf16* W3t = wt + W3T_OFF + r * 8192;
            bf16x8 a0 = *(const bf16x8*)(Hs + ln * LHS + 0 + 8 * qd);
            bf16x8 a1 = *(const bf16x8*)(Hs + ln * LHS + 32 + 8 * qd);
            f32x4 c[8];
            #pragma unroll
            for (int g = 0; g < 2; g++) {          // nt groups 0-3, 4-7
                bf16x8 b[8];
                #pragma unroll
                for (int i = 0; i < 8; i++) {
                    const int nt = g * 4 + (i & 3), ks2 = i >> 2;
                    b[i] = *(const bf16x8*)(W3t + (nt * 16 + ln) * 64 + ks2 * 32 + 8 * qd);
                }
                #pragma unroll
                for (int j = 0; j < 4; j++) {
                    f32x4 acc = {};
                    acc = MFMA(a0, b[j], acc);
                    acc = MFMA(a1, b[4 + j], acc);
                    c[g * 4 + j] = acc;
                }
            }
            #pragma unroll
            for (int nt = 0; nt < 8; nt++) {
                float bv = br3[r * DD + nt * 16 + ln];
                #pragma unroll
                for (int rg = 0; rg < 4; rg++) {
                    float v = c[nt][rg] + bv;
                    Ms[(qd * 4 + rg) * LXS + nt * 16 + ln] = (__bf16)fmaxf(v, 0.f);
                }
            }
        }
        // ---- PROJ: contrib = msg Wpt_r  K=128 N=64 -> ca
        {
            const __bf16* Wpt = wt + WPT_OFF + r * 8192;
            bf16x8 am[4];
            #pragma unroll
            for (int i = 0; i < 4; i++)
                am[i] = *(const bf16x8*)(Ms + ln * LXS + i * 32 + 8 * qd);
            f32x4 c[4] = {};
            #pragma unroll
            for (int g = 0; g < 2; g++) {
                bf16x8 b[8];
                #pragma unroll
                for (int i = 0; i < 8; i++) {
                    const int nt = i & 3, ks4 = g * 2 + (i >> 2);
                    b[i] = *(const bf16x8*)(Wpt + (nt * 16 + ln) * 128 + ks4 * 32 + 8 * qd);
                }
                #pragma unroll
                for (int k2 = 0; k2 < 2; k2++)
                    #pragma unroll
                    for (int nt = 0; nt < 4; nt++)
                        c[nt] = MFMA(am[g * 2 + k2], b[k2 * 4 + nt], c[nt]);
            }
            #pragma unroll
            for (int rg = 0; rg < 4; rg++) {
                const int node = nb0 + m0 + qd * 4 + rg;
                if (node < Nn) {
                    __bf16* cp = ca + ((size_t)r * Nn + node) * HH;
                    #pragma unroll
                    for (int nt = 0; nt < 4; nt++)
                        cp[nt * 16 + ln] = (__bf16)c[nt][rg];
                }
            }
        }
    }
}

// ---------------- node updater MLP (CSR gather of dense contribs) ----------------
__global__ __launch_bounds__(128, 4) void k_node(
    const float* __restrict__ nf,
    const float* __restrict__ bn1, const float* __restrict__ bn2, const float* __restrict__ bn3,
    const __bf16* __restrict__ wt, const __bf16* __restrict__ ca,
    const int* __restrict__ rowStart, const int* __restrict__ csrKey,
    float* __restrict__ out, int Nn)
{
    __shared__ __bf16 smem[NSMEM];
    const int nb0 = blockIdx.x * 32;
    const int tid = threadIdx.x;
    const int w = tid >> 6;
    const int lane = tid & 63;
    const int ln = lane & 15, qd = lane >> 4;
    const int m0 = w << 4;
    __bf16* Xs = smem + w * WBLK;
    __bf16* Hs = smem + w * WBLK + 2176;

    // stage relu(node_feature) rows (coalesced)
    {
        const int m = tid >> 2, q = tid & 3;
        const int node = min(nb0 + m, Nn - 1);
        const float4* rp = (const float4*)(nf + (size_t)node * DD) + 8 * q;
        __bf16* xr = Xs + (m & 15) * LXS + 32 * q;
        #pragma unroll
        for (int jj = 0; jj < 4; jj++) {
            float4 v0 = rp[2 * jj], v1 = rp[2 * jj + 1];
            bf16x8 p;
            p[0] = (__bf16)fmaxf(v0.x, 0.f); p[1] = (__bf16)fmaxf(v0.y, 0.f);
            p[2] = (__bf16)fmaxf(v0.z, 0.f); p[3] = (__bf16)fmaxf(v0.w, 0.f);
            p[4] = (__bf16)fmaxf(v1.x, 0.f); p[5] = (__bf16)fmaxf(v1.y, 0.f);
            p[6] = (__bf16)fmaxf(v1.z, 0.f); p[7] = (__bf16)fmaxf(v1.w, 0.f);
            *(bf16x8*)(xr + 8 * jj) = p;
        }
    }

    bf16x8 ax[4];
    #pragma unroll
    for (int i = 0; i < 4; i++)
        ax[i] = *(const bf16x8*)(Xs + ln * LXS + i * 32 + 8 * qd);

    // gather+sum contribs via CSR (4 independent chains)
    float agg[4][4] = {};
    #pragma unroll
    for (int rg = 0; rg < 4; rg++) {
        const int node = nb0 + m0 + qd * 4 + rg;
        if (node < Nn) {
            const int s0 = rowStart[node], s1 = rowStart[node + 1];
            for (int s = s0; s < s1; s++) {
                const int key = csrKey[s];
                const __bf16* cp = ca + (size_t)key * HH + ln;
                agg[rg][0] += (float)cp[0];
                agg[rg][1] += (float)cp[16];
                agg[rg][2] += (float)cp[32];
                agg[rg][3] += (float)cp[48];
            }
        }
    }

    // GEMM1n: relu(relu(X) Wn1_0 + agg + bn1)  K=128 N=64
    {
        const __bf16* Wt = wt + WN1_OFF;
        f32x4 c[4] = {};
        #pragma unroll
        for (int g = 0; g < 2; g++) {
            bf16x8 b[8];
            #pragma unroll
            for (int i = 0; i < 8; i++) {
                const int nt = i & 3, ks4 = g * 2 + (i >> 2);
                b[i] = *(const bf16x8*)(Wt + (nt * 16 + ln) * 128 + ks4 * 32 + 8 * qd);
            }
            #pragma unroll
            for (int k2 = 0; k2 < 2; k2++)
                #pragma unroll
                for (int nt = 0; nt < 4; nt++)
                    c[nt] = MFMA(ax[g * 2 + k2], b[k2 * 4 + nt], c[nt]);
        }
        #pragma unroll
        for (int nt = 0; nt < 4; nt++) {
            float bv = bn1[nt * 16 + ln];
            #pragma unroll
            for (int rg = 0; rg < 4; rg++) {
                float v = c[nt][rg] + bv + agg[rg][nt];
                Hs[(qd * 4 + rg) * LHS + nt * 16 + ln] = (__bf16)fmaxf(v, 0.f);
            }
        }
    }

    // GEMM2n: K=64 (H2 overlays H1)
    {
        const __bf16* Wt = wt + WN2_OFF;
        bf16x8 a0 = *(const bf16x8*)(Hs + ln * LHS + 0 + 8 * qd);
        bf16x8 a1 = *(const bf16x8*)(Hs + ln * LHS + 32 + 8 * qd);
        bf16x8 b[8];
        #pragma unroll
        for (int i = 0; i < 8; i++) {
            const int nt = i & 3, ks2 = i >> 2;
            b[i] = *(const bf16x8*)(Wt + (nt * 16 + ln) * 64 + ks2 * 32 + 8 * qd);
        }
        f32x4 c[4] = {};
        #pragma unroll
        for (int nt = 0; nt < 4; nt++) {
            c[nt] = MFMA(a0, b[nt], c[nt]);
            c[nt] = MFMA(a1, b[4 + nt], c[nt]);
        }
        #pragma unroll
        for (int nt = 0; nt < 4; nt++) {
            float bv = bn2[nt * 16 + ln];
            #pragma unroll
            for (int rg = 0; rg < 4; rg++) {
                float v = c[nt][rg] + bv;
                Hs[(qd * 4 + rg) * LHS + nt * 16 + ln] = (__bf16)fmaxf(v, 0.f);
            }
        }
    }

    // GEMM3n: K=64 N=128 -> out (+bn3, no relu)
    {
        const __bf16* Wt = wt + WN3_OFF;
        bf16x8 a0 = *(const bf16x8*)(Hs + ln * LHS + 0 + 8 * qd);
        bf16x8 a1 = *(const bf16x8*)(Hs + ln * LHS + 32 + 8 * qd);
        f32x4 c[8];
        #pragma unroll
        for (int g = 0; g < 2; g++) {
            bf16x8 b[8];
            #pragma unroll
            for (int i = 0; i < 8; i++) {
                const int nt = g * 4 + (i & 3), ks2 = i >> 2;
                b[i] = *(const bf16x8*)(Wt + (nt * 16 + ln) * 64 + ks2 * 32 + 8 * qd);
            }
            #pragma unroll
            for (int j = 0; j < 4; j++) {
                f32x4 acc = {};
                acc = MFMA(a0, b[j], acc);
                acc = MFMA(a1, b[4 + j], acc);
                c[g * 4 + j] = acc;
            }
        }
        #pragma unroll
        for (int rg = 0; rg < 4; rg++) {
            const int node = nb0 + m0 + qd * 4 + rg;
            if (node < Nn) {
                float* op = out + (size_t)node * DD;
                #pragma unroll
                for (int nt = 0; nt < 8; nt++)
                    op[nt * 16 + ln] = c[nt][rg] + bn3[nt * 16 + ln];
            }
        }
    }
}

extern "C" void kernel_launch(void* const* d_in, const int* in_sizes, int n_in,
                              void* d_out, int out_size, void* d_ws, size_t ws_size,
                              hipStream_t stream) {
    const float* nf  = (const float*)d_in[0];
    const int*   es  = (const int*)d_in[1];
    const int*   ed  = (const int*)d_in[2];
    const int*   et  = (const int*)d_in[3];
    const float* Wr1 = (const float*)d_in[4];
    const float* br1 = (const float*)d_in[5];
    const float* Wr2 = (const float*)d_in[6];
    const float* br2 = (const float*)d_in[7];
    const float* Wr3 = (const float*)d_in[8];
    const float* br3 = (const float*)d_in[9];
    const float* Wn1 = (const float*)d_in[10];
    const float* bn1 = (const float*)d_in[11];
    const float* Wn2 = (const float*)d_in[12];
    const float* bn2 = (const float*)d_in[13];
    const float* Wn3 = (const float*)d_in[14];
    const float* bn3 = (const float*)d_in[15];
    float* out = (float*)d_out;

    const int Nn = in_sizes[0] / DD;   // 50000
    const int E  = in_sizes[1];        // 200000
    const int NB = (Nn + 1023) / 1024; // <=64

    // workspace layout
    int* p = (int*)d_ws;
    int* dstCnt    = p;                 p += Nn;      // zeroed
    int* dstCursor = p;                 p += Nn;
    int* rowStart  = p;                 p += Nn + 1;
    int* blkSum    = p;                 p += 64;
    int* blkOff    = p;                 p += 64;
    int* csrKey    = p;                 p += E;
    p += ((8 - ((p - (int*)d_ws) & 7)) & 7);          // 32B-align
    __bf16* wbf = (__bf16*)p;           p += (WT_TOTAL + 1) / 2;
    __bf16* ca  = (__bf16*)p;                          // RR*Nn*HH bf16 = 25.6 MB

    hipMemsetAsync((void*)dstCnt, 0, (size_t)Nn * sizeof(int), stream);

    const int nb = (E + NT - 1) / NT;
    k_hist <<<nb, NT, 0, stream>>>(ed, dstCnt, E);
    k_bsum <<<NB, 256, 0, stream>>>(dstCnt, blkSum, Nn);
    k_mid  <<<1, 64, 0, stream>>>(blkSum, blkOff, rowStart, NB, Nn, E);
    k_wout <<<NB, 256, 0, stream>>>(dstCnt, blkOff, rowStart, dstCursor, Nn);
    k_place<<<nb, NT, 0, stream>>>(et, ed, es, dstCursor, csrKey, E, Nn);
    k_prep <<<(WT_TOTAL + NT - 1) / NT, NT, 0, stream>>>(Wr1, Wr2, Wr3, Wn1, Wn2, Wn3, wbf);

    k_dense<<<(Nn + 63) / 64, NT, 0, stream>>>(nf, br1, br2, br3, wbf, ca, Nn);
    k_node <<<(Nn + 31) / 32, 128, 0, stream>>>(nf, bn1, bn2, bn3, wbf, ca, rowStart, csrKey, out, Nn);
}

// Round 7
// 238.026 us; speedup vs baseline: 1.5910x; 1.1635x over previous
//
#include <hip/hip_runtime.h>

#define DD 128
#define HH 64
#define RR 4
#define NT 256

typedef __attribute__((ext_vector_type(8))) __bf16 bf16x8;
typedef __attribute__((ext_vector_type(4))) float f32x4;

// LDS layout (bf16 elements):
//  O_WA  [8192]  W1 (or Wp after re-stage) swizzled, KST=4  (N=64,K=128)
//  O_W2  [4096]  W2 swizzled, KST=2                         (N=64,K=64)
//  O_W3  [8192]  W3 swizzled, KST=2                         (N=128,K=64)
//  O_ACT 4 x 2176 per-wave activation block: X/Ms stride 136, H stride 72
// total 29184 elem = 58368 B  -> 2 blocks/CU
#define O_WA  0
#define O_W2  8192
#define O_W3  12288
#define O_ACT 20480
#define SMEM_ELEMS 29184
#define LXS 136
#define LHS 72
#define ABLK 2176

// transposed bf16 weight pool offsets (elements) in global scratch
#define W1T_OFF 0        // [R][64][128]
#define W2T_OFF 32768    // [R][64][64]
#define W3T_OFF 49152    // [R][128][64]
#define WPT_OFF 81920    // [R][64][128]  (Wn1 slice 1+r)
#define WN1_OFF 114688   // [64][128]     (Wn1 slice 0)
#define WN2_OFF 122880   // [64][64]
#define WN3_OFF 126976   // [128][64]
#define WT_TOTAL 135168

#define MFMA(a, b, c) __builtin_amdgcn_mfma_f32_16x16x32_bf16(a, b, c, 0, 0, 0)

// Stage a [ROWS][COLS] row-major global bf16 matrix into LDS in MFMA-fragment
// order: chunk (row,c8) -> LDS chunk ((row>>4)*KST + (c8>>2))*64 + (c8&3)*16 + (row&15).
// Read side: instr (nt,kk) lane L reads chunk (nt*KST+kk)*64 + L  (perfectly coalesced).
template<int ROWS, int COLS, int KST>
__device__ __forceinline__ void stageSw(const __bf16* __restrict__ g, __bf16* s, int tid) {
    constexpr int CH = COLS / 8;
    constexpr int TOT = ROWS * CH;
    #pragma unroll
    for (int i = tid; i < TOT; i += NT) {
        const int row = i / CH, c8 = i & (CH - 1);
        const int idx = (((row >> 4) * KST + (c8 >> 2)) * 64 + (c8 & 3) * 16 + (row & 15)) * 8;
        *(bf16x8*)(s + idx) = *(const bf16x8*)(g + row * COLS + c8 * 8);
    }
}

// ---------------- dst histogram ----------------
__global__ void k_hist(const int* __restrict__ ed, int* __restrict__ dstCnt, int E) {
    int i = blockIdx.x * blockDim.x + threadIdx.x;
    if (i < E) atomicAdd(&dstCnt[ed[i]], 1);
}

// ---------------- parallel CSR scan ----------------
__global__ void k_bsum(const int* __restrict__ dstCnt, int* __restrict__ blkSum, int Nn) {
    int b = blockIdx.x, t = threadIdx.x;
    int g = b * 1024 + t * 4;
    int s = 0;
    if (g + 3 < Nn) { int4 v = *(const int4*)(dstCnt + g); s = v.x + v.y + v.z + v.w; }
    else { for (int k = 0; k < 4; k++) if (g + k < Nn) s += dstCnt[g + k]; }
    for (int off = 32; off > 0; off >>= 1) s += __shfl_down(s, off);
    __shared__ int ws[4];
    if ((t & 63) == 0) ws[t >> 6] = s;
    __syncthreads();
    if (t == 0) blkSum[b] = ws[0] + ws[1] + ws[2] + ws[3];
}

__global__ void k_mid(const int* __restrict__ blkSum, int* __restrict__ blkOff,
                      int* __restrict__ rowStart, int NB, int Nn, int E) {
    int lane = threadIdx.x;
    int s = (lane < NB) ? blkSum[lane] : 0;
    int sc = s;
    #pragma unroll
    for (int off = 1; off < 64; off <<= 1) { int u = __shfl_up(sc, off); if (lane >= off) sc += u; }
    if (lane < NB) blkOff[lane] = sc - s;
    if (lane == 0) rowStart[Nn] = E;
}

__global__ void k_wout(const int* __restrict__ dstCnt, const int* __restrict__ blkOff,
                       int* __restrict__ rowStart, int* __restrict__ dstCursor, int Nn) {
    int b = blockIdx.x, t = threadIdx.x;
    int g = b * 1024 + t * 4;
    int4 v = {0, 0, 0, 0};
    bool full = (g + 3 < Nn);
    if (full) v = *(const int4*)(dstCnt + g);
    else {
        if (g     < Nn) v.x = dstCnt[g];
        if (g + 1 < Nn) v.y = dstCnt[g + 1];
        if (g + 2 < Nn) v.z = dstCnt[g + 2];
    }
    int s = v.x + v.y + v.z + v.w;
    int lane = t & 63, wv = t >> 6;
    int sc = s;
    #pragma unroll
    for (int off = 1; off < 64; off <<= 1) { int u = __shfl_up(sc, off); if (lane >= off) sc += u; }
    __shared__ int wsum[4];
    if (lane == 63) wsum[wv] = sc;
    __syncthreads();
    int wadd = 0;
    for (int i = 0; i < wv; i++) wadd += wsum[i];
    int e0 = blkOff[b] + wadd + sc - s;
    int4 rs; rs.x = e0; rs.y = e0 + v.x; rs.z = rs.y + v.y; rs.w = rs.z + v.z;
    if (full) { *(int4*)(rowStart + g) = rs; *(int4*)(dstCursor + g) = rs; }
    else {
        int a[4] = {rs.x, rs.y, rs.z, rs.w};
        for (int k = 0; k < 4; k++) if (g + k < Nn) { rowStart[g + k] = a[k]; dstCursor[g + k] = a[k]; }
    }
}

// ---------------- CSR fill: per edge store packed (type*Nn + src) key ----------------
__global__ void k_place(const int* __restrict__ et, const int* __restrict__ ed,
                        const int* __restrict__ es, int* __restrict__ dstCursor,
                        int* __restrict__ csrKey, int E, int Nn) {
    int i = blockIdx.x * blockDim.x + threadIdx.x;
    if (i < E) {
        int sl = atomicAdd(&dstCursor[ed[i]], 1);
        csrKey[sl] = et[i] * Nn + es[i];
    }
}

// ---------------- weight transpose+convert ----------------
__global__ void k_prep(const float* __restrict__ Wr1, const float* __restrict__ Wr2,
                       const float* __restrict__ Wr3, const float* __restrict__ Wn1,
                       const float* __restrict__ Wn2, const float* __restrict__ Wn3,
                       __bf16* __restrict__ wt) {
    int i = blockIdx.x * blockDim.x + threadIdx.x;
    float v;
    if (i < 32768) {                       // W1t [r][n64][k128]
        int r = i >> 13, n = (i >> 7) & 63, k = i & 127;
        v = Wr1[r * 8192 + k * 64 + n];
    } else if (i < 49152) {                // W2t [r][n64][k64]
        int j = i - 32768; int r = j >> 12, n = (j >> 6) & 63, k = j & 63;
        v = Wr2[r * 4096 + k * 64 + n];
    } else if (i < 81920) {                // W3t [r][n128][k64]
        int j = i - 49152; int r = j >> 13, n = (j >> 6) & 127, k = j & 63;
        v = Wr3[r * 8192 + k * 128 + n];
    } else if (i < 114688) {               // Wpt [r][n64][k128]
        int j = i - 81920; int r = j >> 13, n = (j >> 7) & 63, k = j & 127;
        v = Wn1[((1 + r) * 128 + k) * 64 + n];
    } else if (i < 122880) {               // Wn1t0 [n64][k128]
        int j = i - 114688; int n = j >> 7, k = j & 127;
        v = Wn1[k * 64 + n];
    } else if (i < 126976) {               // Wn2t [n64][k64]
        int j = i - 122880; int n = j >> 6, k = j & 63;
        v = Wn2[k * 64 + n];
    } else if (i < WT_TOTAL) {             // Wn3t [n128][k64]
        int j = i - 126976; int n = j >> 6, k = j & 63;
        v = Wn3[k * 128 + n];
    } else return;
    wt[i] = (__bf16)v;
}

// ---------------- dense message+projection: one relation per block ----------------
__global__ __launch_bounds__(NT, 2) void k_dense(
    const float* __restrict__ nf,
    const float* __restrict__ br1, const float* __restrict__ br2, const float* __restrict__ br3,
    const __bf16* __restrict__ wt, __bf16* __restrict__ ca, int Nn)
{
    __shared__ __bf16 smem[SMEM_ELEMS];
    const int r   = blockIdx.y;
    const int nb0 = blockIdx.x * 64;
    const int tid = threadIdx.x;
    const int w = tid >> 6;
    const int lane = tid & 63;
    const int ln = lane & 15, qd = lane >> 4;
    __bf16* act = smem + O_ACT + w * ABLK;

    // ---- cooperative staging: weights (swizzled) + X rows
    stageSw<64, 128, 4>(wt + W1T_OFF + r * 8192, smem + O_WA, tid);
    stageSw<64,  64, 2>(wt + W2T_OFF + r * 4096, smem + O_W2, tid);
    stageSw<128, 64, 2>(wt + W3T_OFF + r * 8192, smem + O_W3, tid);
    {
        const int m = tid >> 2, q = tid & 3;
        const int node = min(nb0 + m, Nn - 1);
        const float4* rp = (const float4*)(nf + (size_t)node * DD) + 8 * q;
        __bf16* xr = smem + O_ACT + (m >> 4) * ABLK + (m & 15) * LXS + 32 * q;
        #pragma unroll
        for (int jj = 0; jj < 4; jj++) {
            float4 v0 = rp[2 * jj], v1 = rp[2 * jj + 1];
            bf16x8 p;
            p[0] = (__bf16)v0.x; p[1] = (__bf16)v0.y; p[2] = (__bf16)v0.z; p[3] = (__bf16)v0.w;
            p[4] = (__bf16)v1.x; p[5] = (__bf16)v1.y; p[6] = (__bf16)v1.z; p[7] = (__bf16)v1.w;
            *(bf16x8*)(xr + 8 * jj) = p;
        }
    }
    __syncthreads();

    // A-frags of X in regs (act region then reusable)
    bf16x8 ax[4];
    #pragma unroll
    for (int i = 0; i < 4; i++)
        ax[i] = *(const bf16x8*)(act + ln * LXS + i * 32 + 8 * qd);

    // ---- GEMM1: h1 = relu(X W1 + b1)   K=128 N=64, B from LDS
    {
        f32x4 c[4] = {};
        #pragma unroll
        for (int kk = 0; kk < 4; kk++)
            #pragma unroll
            for (int nt = 0; nt < 4; nt++) {
                bf16x8 b = *(const bf16x8*)(smem + O_WA + ((nt * 4 + kk) * 64 + lane) * 8);
                c[nt] = MFMA(ax[kk], b, c[nt]);
            }
        #pragma unroll
        for (int nt = 0; nt < 4; nt++) {
            float bv = br1[r * HH + nt * 16 + ln];
            #pragma unroll
            for (int rg = 0; rg < 4; rg++) {
                float v = c[nt][rg] + bv;
                act[(qd * 4 + rg) * LHS + nt * 16 + ln] = (__bf16)fmaxf(v, 0.f);  // H1
            }
        }
    }
    // ---- GEMM2: h2 = relu(h1 W2 + b2)  K=64 (H2 overlays H1; wave-local in-order)
    {
        bf16x8 a0 = *(const bf16x8*)(act + ln * LHS + 0 + 8 * qd);
        bf16x8 a1 = *(const bf16x8*)(act + ln * LHS + 32 + 8 * qd);
        f32x4 c[4] = {};
        #pragma unroll
        for (int nt = 0; nt < 4; nt++) {
            bf16x8 b0 = *(const bf16x8*)(smem + O_W2 + ((nt * 2 + 0) * 64 + lane) * 8);
            bf16x8 b1 = *(const bf16x8*)(smem + O_W2 + ((nt * 2 + 1) * 64 + lane) * 8);
            c[nt] = MFMA(a0, b0, c[nt]);
            c[nt] = MFMA(a1, b1, c[nt]);
        }
        #pragma unroll
        for (int nt = 0; nt < 4; nt++) {
            float bv = br2[r * HH + nt * 16 + ln];
            #pragma unroll
            for (int rg = 0; rg < 4; rg++) {
                float v = c[nt][rg] + bv;
                act[(qd * 4 + rg) * LHS + nt * 16 + ln] = (__bf16)fmaxf(v, 0.f);  // H2
            }
        }
    }
    // ---- GEMM3: msg = relu(h2 W3 + b3)  N=128 K=64 -> Ms (act, stride LXS)
    {
        bf16x8 a0 = *(const bf16x8*)(act + ln * LHS + 0 + 8 * qd);
        bf16x8 a1 = *(const bf16x8*)(act + ln * LHS + 32 + 8 * qd);
        f32x4 c[8];
        #pragma unroll
        for (int nt = 0; nt < 8; nt++) {
            bf16x8 b0 = *(const bf16x8*)(smem + O_W3 + ((nt * 2 + 0) * 64 + lane) * 8);
            bf16x8 b1 = *(const bf16x8*)(smem + O_W3 + ((nt * 2 + 1) * 64 + lane) * 8);
            f32x4 acc = {};
            acc = MFMA(a0, b0, acc);
            acc = MFMA(a1, b1, acc);
            c[nt] = acc;
        }
        #pragma unroll
        for (int nt = 0; nt < 8; nt++) {
            float bv = br3[r * DD + nt * 16 + ln];
            #pragma unroll
            for (int rg = 0; rg < 4; rg++) {
                float v = c[nt][rg] + bv;
                act[(qd * 4 + rg) * LXS + nt * 16 + ln] = (__bf16)fmaxf(v, 0.f);  // Ms
            }
        }
    }
    // ---- re-stage Wp over WA (all waves past GEMM1 reads), then PROJ
    __syncthreads();
    stageSw<64, 128, 4>(wt + WPT_OFF + r * 8192, smem + O_WA, tid);
    __syncthreads();
    {
        bf16x8 am[4];
        #pragma unroll
        for (int i = 0; i < 4; i++)
            am[i] = *(const bf16x8*)(act + ln * LXS + i * 32 + 8 * qd);
        f32x4 c[4] = {};
        #pragma unroll
        for (int kk = 0; kk < 4; kk++)
            #pragma unroll
            for (int nt = 0; nt < 4; nt++) {
                bf16x8 b = *(const bf16x8*)(smem + O_WA + ((nt * 4 + kk) * 64 + lane) * 8);
                c[nt] = MFMA(am[kk], b, c[nt]);
            }
        const int m0 = w << 4;
        #pragma unroll
        for (int rg = 0; rg < 4; rg++) {
            const int node = nb0 + m0 + qd * 4 + rg;
            if (node < Nn) {
                __bf16* cp = ca + ((size_t)r * Nn + node) * HH;
                #pragma unroll
                for (int nt = 0; nt < 4; nt++)
                    cp[nt * 16 + ln] = (__bf16)c[nt][rg];
            }
        }
    }
}

// ---------------- node updater MLP (weights in LDS; CSR gather of contribs) ----------------
__global__ __launch_bounds__(NT, 2) void k_node(
    const float* __restrict__ nf,
    const float* __restrict__ bn1, const float* __restrict__ bn2, const float* __restrict__ bn3,
    const __bf16* __restrict__ wt, const __bf16* __restrict__ ca,
    const int* __restrict__ rowStart, const int* __restrict__ csrKey,
    float* __restrict__ out, int Nn)
{
    __shared__ __bf16 smem[SMEM_ELEMS];
    const int nb0 = blockIdx.x * 64;
    const int tid = threadIdx.x;
    const int w = tid >> 6;
    const int lane = tid & 63;
    const int ln = lane & 15, qd = lane >> 4;
    const int m0 = w << 4;
    __bf16* act = smem + O_ACT + w * ABLK;

    stageSw<64, 128, 4>(wt + WN1_OFF, smem + O_WA, tid);
    stageSw<64,  64, 2>(wt + WN2_OFF, smem + O_W2, tid);
    stageSw<128, 64, 2>(wt + WN3_OFF, smem + O_W3, tid);
    {
        const int m = tid >> 2, q = tid & 3;
        const int node = min(nb0 + m, Nn - 1);
        const float4* rp = (const float4*)(nf + (size_t)node * DD) + 8 * q;
        __bf16* xr = smem + O_ACT + (m >> 4) * ABLK + (m & 15) * LXS + 32 * q;
        #pragma unroll
        for (int jj = 0; jj < 4; jj++) {
            float4 v0 = rp[2 * jj], v1 = rp[2 * jj + 1];
            bf16x8 p;
            p[0] = (__bf16)fmaxf(v0.x, 0.f); p[1] = (__bf16)fmaxf(v0.y, 0.f);
            p[2] = (__bf16)fmaxf(v0.z, 0.f); p[3] = (__bf16)fmaxf(v0.w, 0.f);
            p[4] = (__bf16)fmaxf(v1.x, 0.f); p[5] = (__bf16)fmaxf(v1.y, 0.f);
            p[6] = (__bf16)fmaxf(v1.z, 0.f); p[7] = (__bf16)fmaxf(v1.w, 0.f);
            *(bf16x8*)(xr + 8 * jj) = p;
        }
    }
    __syncthreads();

    bf16x8 ax[4];
    #pragma unroll
    for (int i = 0; i < 4; i++)
        ax[i] = *(const bf16x8*)(act + ln * LXS + i * 32 + 8 * qd);

    // CSR gather of contribs (4 independent chains; overlaps with GEMM1 via scheduler)
    float agg[4][4] = {};
    #pragma unroll
    for (int rg = 0; rg < 4; rg++) {
        const int node = nb0 + m0 + qd * 4 + rg;
        if (node < Nn) {
            const int s0 = rowStart[node], s1 = rowStart[node + 1];
            for (int s = s0; s < s1; s++) {
                const int key = csrKey[s];
                const __bf16* cp = ca + (size_t)key * HH + ln;
                agg[rg][0] += (float)cp[0];
                agg[rg][1] += (float)cp[16];
                agg[rg][2] += (float)cp[32];
                agg[rg][3] += (float)cp[48];
            }
        }
    }

    // GEMM1n
    {
        f32x4 c[4] = {};
        #pragma unroll
        for (int kk = 0; kk < 4; kk++)
            #pragma unroll
            for (int nt = 0; nt < 4; nt++) {
                bf16x8 b = *(const bf16x8*)(smem + O_WA + ((nt * 4 + kk) * 64 + lane) * 8);
                c[nt] = MFMA(ax[kk], b, c[nt]);
            }
        #pragma unroll
        for (int nt = 0; nt < 4; nt++) {
            float bv = bn1[nt * 16 + ln];
            #pragma unroll
            for (int rg = 0; rg < 4; rg++) {
                float v = c[nt][rg] + bv + agg[rg][nt];
                act[(qd * 4 + rg) * LHS + nt * 16 + ln] = (__bf16)fmaxf(v, 0.f);
            }
        }
    }
    // GEMM2n
    {
        bf16x8 a0 = *(const bf16x8*)(act + ln * LHS + 0 + 8 * qd);
        bf16x8 a1 = *(const bf16x8*)(act + ln * LHS + 32 + 8 * qd);
        f32x4 c[4] = {};
        #pragma unroll
        for (int nt = 0; nt < 4; nt++) {
            bf16x8 b0 = *(const bf16x8*)(smem + O_W2 + ((nt * 2 + 0) * 64 + lane) * 8);
            bf16x8 b1 = *(const bf16x8*)(smem + O_W2 + ((nt * 2 + 1) * 64 + lane) * 8);
            c[nt] = MFMA(a0, b0, c[nt]);
            c[nt] = MFMA(a1, b1, c[nt]);
        }
        #pragma unroll
        for (int nt = 0; nt < 4; nt++) {
            float bv = bn2[nt * 16 + ln];
            #pragma unroll
            for (int rg = 0; rg < 4; rg++) {
                float v = c[nt][rg] + bv;
                act[(qd * 4 + rg) * LHS + nt * 16 + ln] = (__bf16)fmaxf(v, 0.f);
            }
        }
    }
    // GEMM3n -> out
    {
        bf16x8 a0 = *(const bf16x8*)(act + ln * LHS + 0 + 8 * qd);
        bf16x8 a1 = *(const bf16x8*)(act + ln * LHS + 32 + 8 * qd);
        f32x4 c[8];
        #pragma unroll
        for (int nt = 0; nt < 8; nt++) {
            bf16x8 b0 = *(const bf16x8*)(smem + O_W3 + ((nt * 2 + 0) * 64 + lane) * 8);
            bf16x8 b1 = *(const bf16x8*)(smem + O_W3 + ((nt * 2 + 1) * 64 + lane) * 8);
            f32x4 acc = {};
            acc = MFMA(a0, b0, acc);
            acc = MFMA(a1, b1, acc);
            c[nt] = acc;
        }
        #pragma unroll
        for (int rg = 0; rg < 4; rg++) {
            const int node = nb0 + m0 + qd * 4 + rg;
            if (node < Nn) {
                float* op = out + (size_t)node * DD;
                #pragma unroll
                for (int nt = 0; nt < 8; nt++)
                    op[nt * 16 + ln] = c[nt][rg] + bn3[nt * 16 + ln];
            }
        }
    }
}

extern "C" void kernel_launch(void* const* d_in, const int* in_sizes, int n_in,
                              void* d_out, int out_size, void* d_ws, size_t ws_size,
                              hipStream_t stream) {
    const float* nf  = (const float*)d_in[0];
    const int*   es  = (const int*)d_in[1];
    const int*   ed  = (const int*)d_in[2];
    const int*   et  = (const int*)d_in[3];
    const float* Wr1 = (const float*)d_in[4];
    const float* br1 = (const float*)d_in[5];
    const float* Wr2 = (const float*)d_in[6];
    const float* br2 = (const float*)d_in[7];
    const float* Wr3 = (const float*)d_in[8];
    const float* br3 = (const float*)d_in[9];
    const float* Wn1 = (const float*)d_in[10];
    const float* bn1 = (const float*)d_in[11];
    const float* Wn2 = (const float*)d_in[12];
    const float* bn2 = (const float*)d_in[13];
    const float* Wn3 = (const float*)d_in[14];
    const float* bn3 = (const float*)d_in[15];
    float* out = (float*)d_out;

    const int Nn = in_sizes[0] / DD;   // 50000
    const int E  = in_sizes[1];        // 200000
    const int NB = (Nn + 1023) / 1024; // <=64

    int* p = (int*)d_ws;
    int* dstCnt    = p;                 p += Nn;      // zeroed
    int* dstCursor = p;                 p += Nn;
    int* rowStart  = p;                 p += Nn + 1;
    int* blkSum    = p;                 p += 64;
    int* blkOff    = p;                 p += 64;
    int* csrKey    = p;                 p += E;
    p += ((8 - ((p - (int*)d_ws) & 7)) & 7);          // 32B-align
    __bf16* wbf = (__bf16*)p;           p += (WT_TOTAL + 1) / 2;
    __bf16* ca  = (__bf16*)p;                          // RR*Nn*HH bf16 = 25.6 MB

    hipMemsetAsync((void*)dstCnt, 0, (size_t)Nn * sizeof(int), stream);

    const int nb = (E + NT - 1) / NT;
    k_hist <<<nb, NT, 0, stream>>>(ed, dstCnt, E);
    k_bsum <<<NB, 256, 0, stream>>>(dstCnt, blkSum, Nn);
    k_mid  <<<1, 64, 0, stream>>>(blkSum, blkOff, rowStart, NB, Nn, E);
    k_wout <<<NB, 256, 0, stream>>>(dstCnt, blkOff, rowStart, dstCursor, Nn);
    k_place<<<nb, NT, 0, stream>>>(et, ed, es, dstCursor, csrKey, E, Nn);
    k_prep <<<(WT_TOTAL + NT - 1) / NT, NT, 0, stream>>>(Wr1, Wr2, Wr3, Wn1, Wn2, Wn3, wbf);

    dim3 gd((Nn + 63) / 64, RR);
    k_dense<<<gd, NT, 0, stream>>>(nf, br1, br2, br3, wbf, ca, Nn);
    k_node <<<(Nn + 63) / 64, NT, 0, stream>>>(nf, bn1, bn2, bn3, wbf, ca, rowStart, csrKey, out, Nn);
}

// Round 8
// 235.266 us; speedup vs baseline: 1.6096x; 1.0117x over previous
//
#include <hip/hip_runtime.h>

#define DD 128
#define HH 64
#define RR 4
#define NT 256

typedef __attribute__((ext_vector_type(8))) __bf16 bf16x8;
typedef __attribute__((ext_vector_type(4))) float f32x4;

// LDS row strides (bf16 elements). Odd multiples of 8 -> every 8-lane phase of a
// b128 read/write hits distinct bank-quads (conflict-free both directions).
#define SK128 136   // K=128 rows (+8 pad)
#define SK64  72    // K=64 rows  (+8 pad)
#define ABLK  2176  // per-wave act block: H rows (SK64) overlay low part, Ms rows (SK128)

// k_dense dynamic LDS layout (elements)
#define O_W1  0                    // 64 x 136 = 8704
#define O_W2  8704                 // 64 x 72  = 4608
#define O_W3  13312                // 128 x 72 = 9216
#define O_WP  22528                // 64 x 136 = 8704
#define O_ACT 31232                // 4 x 2176 = 8704
#define DSMEM_ELEMS 39936          // 79872 B -> 2 blocks/CU (dynamic)
// k_node static LDS layout
#define N_W1  0
#define N_W2  8704
#define N_W3  13312
#define N_ACT 22528
#define NSMEM_ELEMS 31232          // 62464 B static

// global bf16 weight pool offsets (elements), all matrices [n][k] row-major
#define W1T_OFF 0        // [R][64][128]
#define W2T_OFF 32768    // [R][64][64]
#define W3T_OFF 49152    // [R][128][64]
#define WPT_OFF 81920    // [R][64][128]  (Wn1 slice 1+r)
#define WN1_OFF 114688   // [64][128]     (Wn1 slice 0)
#define WN2_OFF 122880   // [64][64]
#define WN3_OFF 126976   // [128][64]
#define WT_TOTAL 135168

#define MFMA(a, b, c) __builtin_amdgcn_mfma_f32_16x16x32_bf16(a, b, c, 0, 0, 0)

// Stage [ROWS][COLS] row-major global -> LDS rows with padded STRIDE.
// Consecutive tids: consecutive global chunks (coalesced) AND consecutive LDS
// bytes within a row (conflict-free b128 writes; row step lands on rotated banks).
template<int ROWS, int COLS, int STRIDE>
__device__ __forceinline__ void stageRM(const __bf16* __restrict__ g, __bf16* s, int tid) {
    constexpr int CH = COLS / 8;
    constexpr int TOT = ROWS * CH;
    #pragma unroll
    for (int i = tid; i < TOT; i += NT) {
        const int row = i / CH, c8 = i % CH;
        *(bf16x8*)(s + row * STRIDE + c8 * 8) = *(const bf16x8*)(g + row * COLS + c8 * 8);
    }
}

// ---------------- dst histogram ----------------
__global__ void k_hist(const int* __restrict__ ed, int* __restrict__ dstCnt, int E) {
    int i = blockIdx.x * blockDim.x + threadIdx.x;
    if (i < E) atomicAdd(&dstCnt[ed[i]], 1);
}

// ---------------- parallel CSR scan ----------------
__global__ void k_bsum(const int* __restrict__ dstCnt, int* __restrict__ blkSum, int Nn) {
    int b = blockIdx.x, t = threadIdx.x;
    int g = b * 1024 + t * 4;
    int s = 0;
    if (g + 3 < Nn) { int4 v = *(const int4*)(dstCnt + g); s = v.x + v.y + v.z + v.w; }
    else { for (int k = 0; k < 4; k++) if (g + k < Nn) s += dstCnt[g + k]; }
    for (int off = 32; off > 0; off >>= 1) s += __shfl_down(s, off);
    __shared__ int ws[4];
    if ((t & 63) == 0) ws[t >> 6] = s;
    __syncthreads();
    if (t == 0) blkSum[b] = ws[0] + ws[1] + ws[2] + ws[3];
}

__global__ void k_mid(const int* __restrict__ blkSum, int* __restrict__ blkOff,
                      int* __restrict__ rowStart, int NB, int Nn, int E) {
    int lane = threadIdx.x;
    int s = (lane < NB) ? blkSum[lane] : 0;
    int sc = s;
    #pragma unroll
    for (int off = 1; off < 64; off <<= 1) { int u = __shfl_up(sc, off); if (lane >= off) sc += u; }
    if (lane < NB) blkOff[lane] = sc - s;
    if (lane == 0) rowStart[Nn] = E;
}

__global__ void k_wout(const int* __restrict__ dstCnt, const int* __restrict__ blkOff,
                       int* __restrict__ rowStart, int* __restrict__ dstCursor, int Nn) {
    int b = blockIdx.x, t = threadIdx.x;
    int g = b * 1024 + t * 4;
    int4 v = {0, 0, 0, 0};
    bool full = (g + 3 < Nn);
    if (full) v = *(const int4*)(dstCnt + g);
    else {
        if (g     < Nn) v.x = dstCnt[g];
        if (g + 1 < Nn) v.y = dstCnt[g + 1];
        if (g + 2 < Nn) v.z = dstCnt[g + 2];
    }
    int s = v.x + v.y + v.z + v.w;
    int lane = t & 63, wv = t >> 6;
    int sc = s;
    #pragma unroll
    for (int off = 1; off < 64; off <<= 1) { int u = __shfl_up(sc, off); if (lane >= off) sc += u; }
    __shared__ int wsum[4];
    if (lane == 63) wsum[wv] = sc;
    __syncthreads();
    int wadd = 0;
    for (int i = 0; i < wv; i++) wadd += wsum[i];
    int e0 = blkOff[b] + wadd + sc - s;
    int4 rs; rs.x = e0; rs.y = e0 + v.x; rs.z = rs.y + v.y; rs.w = rs.z + v.z;
    if (full) { *(int4*)(rowStart + g) = rs; *(int4*)(dstCursor + g) = rs; }
    else {
        int a[4] = {rs.x, rs.y, rs.z, rs.w};
        for (int k = 0; k < 4; k++) if (g + k < Nn) { rowStart[g + k] = a[k]; dstCursor[g + k] = a[k]; }
    }
}

// ---------------- CSR fill: per edge store packed (type*Nn + src) key ----------------
__global__ void k_place(const int* __restrict__ et, const int* __restrict__ ed,
                        const int* __restrict__ es, int* __restrict__ dstCursor,
                        int* __restrict__ csrKey, int E, int Nn) {
    int i = blockIdx.x * blockDim.x + threadIdx.x;
    if (i < E) {
        int sl = atomicAdd(&dstCursor[ed[i]], 1);
        csrKey[sl] = et[i] * Nn + es[i];
    }
}

// ---------------- weight transpose+convert (input-coalesced reads) ----------------
__global__ void k_prep(const float* __restrict__ Wr1, const float* __restrict__ Wr2,
                       const float* __restrict__ Wr3, const float* __restrict__ Wn1,
                       const float* __restrict__ Wn2, const float* __restrict__ Wn3,
                       __bf16* __restrict__ wt) {
    int i = blockIdx.x * blockDim.x + threadIdx.x;
    if (i < 32768) {                                  // Wr1 [r][k128][n64] -> W1t [r][n][k]
        int r = i >> 13, k = (i >> 6) & 127, n = i & 63;
        wt[W1T_OFF + r * 8192 + n * 128 + k] = (__bf16)Wr1[i];
    } else if (i < 49152) {                           // Wr2 [r][k64][n64]
        int j = i - 32768; int r = j >> 12, k = (j >> 6) & 63, n = j & 63;
        wt[W2T_OFF + r * 4096 + n * 64 + k] = (__bf16)Wr2[j];
    } else if (i < 81920) {                           // Wr3 [r][k64][n128]
        int j = i - 49152; int r = j >> 13, k = (j >> 7) & 63, n = j & 127;
        wt[W3T_OFF + r * 8192 + n * 64 + k] = (__bf16)Wr3[j];
    } else if (i < 122880) {                          // Wn1 [(R+1)*128][64]
        int j = i - 81920; int row = j >> 6, n = j & 63;
        int s = row >> 7, k = row & 127;
        float v = Wn1[j];
        if (s == 0) wt[WN1_OFF + n * 128 + k] = (__bf16)v;
        else        wt[WPT_OFF + (s - 1) * 8192 + n * 128 + k] = (__bf16)v;
    } else if (i < 126976) {                          // Wn2 [k64][n64]
        int j = i - 122880; int k = j >> 6, n = j & 63;
        wt[WN2_OFF + n * 64 + k] = (__bf16)Wn2[j];
    } else if (i < WT_TOTAL) {                        // Wn3 [k64][n128]
        int j = i - 126976; int k = j >> 7, n = j & 127;
        wt[WN3_OFF + n * 64 + k] = (__bf16)Wn3[j];
    }
}

// ---------------- dense message+projection: one relation per block, 1 barrier ----------------
__global__ __launch_bounds__(NT, 2) void k_dense(
    const float* __restrict__ nf,
    const float* __restrict__ br1, const float* __restrict__ br2, const float* __restrict__ br3,
    const __bf16* __restrict__ wt, __bf16* __restrict__ ca, int Nn)
{
    extern __shared__ __bf16 smem[];
    const int r   = blockIdx.y;
    const int nb0 = blockIdx.x * 64;
    const int tid = threadIdx.x;
    const int w = tid >> 6;
    const int lane = tid & 63;
    const int ln = lane & 15, qd = lane >> 4;
    __bf16* act = smem + O_ACT + w * ABLK;

    // ---- cooperative staging: 4 weight matrices (padded row-major) + X rows (wave-local)
    stageRM<64, 128, SK128>(wt + W1T_OFF + r * 8192, smem + O_W1, tid);
    stageRM<64,  64, SK64 >(wt + W2T_OFF + r * 4096, smem + O_W2, tid);
    stageRM<128, 64, SK64 >(wt + W3T_OFF + r * 8192, smem + O_W3, tid);
    stageRM<64, 128, SK128>(wt + WPT_OFF + r * 8192, smem + O_WP, tid);
    {
        const int m = tid >> 2, q = tid & 3;   // m in [16w,16w+16) -> wave-local
        const int node = min(nb0 + m, Nn - 1);
        const float4* rp = (const float4*)(nf + (size_t)node * DD) + 8 * q;
        __bf16* xr = act + (m & 15) * SK128 + 32 * q;
        #pragma unroll
        for (int jj = 0; jj < 4; jj++) {
            float4 v0 = rp[2 * jj], v1 = rp[2 * jj + 1];
            bf16x8 p;
            p[0] = (__bf16)v0.x; p[1] = (__bf16)v0.y; p[2] = (__bf16)v0.z; p[3] = (__bf16)v0.w;
            p[4] = (__bf16)v1.x; p[5] = (__bf16)v1.y; p[6] = (__bf16)v1.z; p[7] = (__bf16)v1.w;
            *(bf16x8*)(xr + 8 * jj) = p;
        }
    }
    // A-frags of X (wave-local LDS, no barrier needed for own writes)
    bf16x8 ax[4];
    #pragma unroll
    for (int i = 0; i < 4; i++)
        ax[i] = *(const bf16x8*)(act + ln * SK128 + i * 32 + 8 * qd);
    __syncthreads();   // weights ready (the only barrier)

    // ---- GEMM1: h1 = relu(X W1 + b1)   K=128 N=64
    {
        f32x4 c[4] = {};
        #pragma unroll
        for (int kk = 0; kk < 4; kk++)
            #pragma unroll
            for (int nt = 0; nt < 4; nt++) {
                bf16x8 b = *(const bf16x8*)(smem + O_W1 + (nt * 16 + ln) * SK128 + kk * 32 + 8 * qd);
                c[nt] = MFMA(ax[kk], b, c[nt]);
            }
        #pragma unroll
        for (int nt = 0; nt < 4; nt++) {
            float bv = br1[r * HH + nt * 16 + ln];
            #pragma unroll
            for (int rg = 0; rg < 4; rg++) {
                float v = c[nt][rg] + bv;
                act[(qd * 4 + rg) * SK64 + nt * 16 + ln] = (__bf16)fmaxf(v, 0.f);  // H1
            }
        }
    }
    // ---- GEMM2: h2 = relu(h1 W2 + b2)  K=64 (H2 overlays H1)
    {
        bf16x8 a0 = *(const bf16x8*)(act + ln * SK64 + 0 + 8 * qd);
        bf16x8 a1 = *(const bf16x8*)(act + ln * SK64 + 32 + 8 * qd);
        f32x4 c[4] = {};
        #pragma unroll
        for (int nt = 0; nt < 4; nt++) {
            bf16x8 b0 = *(const bf16x8*)(smem + O_W2 + (nt * 16 + ln) * SK64 + 0 + 8 * qd);
            bf16x8 b1 = *(const bf16x8*)(smem + O_W2 + (nt * 16 + ln) * SK64 + 32 + 8 * qd);
            c[nt] = MFMA(a0, b0, c[nt]);
            c[nt] = MFMA(a1, b1, c[nt]);
        }
        #pragma unroll
        for (int nt = 0; nt < 4; nt++) {
            float bv = br2[r * HH + nt * 16 + ln];
            #pragma unroll
            for (int rg = 0; rg < 4; rg++) {
                float v = c[nt][rg] + bv;
                act[(qd * 4 + rg) * SK64 + nt * 16 + ln] = (__bf16)fmaxf(v, 0.f);  // H2
            }
        }
    }
    // ---- GEMM3: msg = relu(h2 W3 + b3)  N=128 K=64 -> Ms (overlays act, stride SK128)
    {
        bf16x8 a0 = *(const bf16x8*)(act + ln * SK64 + 0 + 8 * qd);
        bf16x8 a1 = *(const bf16x8*)(act + ln * SK64 + 32 + 8 * qd);
        f32x4 c[8];
        #pragma unroll
        for (int nt = 0; nt < 8; nt++) {
            bf16x8 b0 = *(const bf16x8*)(smem + O_W3 + (nt * 16 + ln) * SK64 + 0 + 8 * qd);
            bf16x8 b1 = *(const bf16x8*)(smem + O_W3 + (nt * 16 + ln) * SK64 + 32 + 8 * qd);
            f32x4 acc = {};
            acc = MFMA(a0, b0, acc);
            acc = MFMA(a1, b1, acc);
            c[nt] = acc;
        }
        #pragma unroll
        for (int nt = 0; nt < 8; nt++) {
            float bv = br3[r * DD + nt * 16 + ln];
            #pragma unroll
            for (int rg = 0; rg < 4; rg++) {
                float v = c[nt][rg] + bv;
                act[(qd * 4 + rg) * SK128 + nt * 16 + ln] = (__bf16)fmaxf(v, 0.f);  // Ms
            }
        }
    }
    // ---- PROJ: contrib = msg Wp_r  K=128 N=64 -> ca
    {
        bf16x8 am[4];
        #pragma unroll
        for (int i = 0; i < 4; i++)
            am[i] = *(const bf16x8*)(act + ln * SK128 + i * 32 + 8 * qd);
        f32x4 c[4] = {};
        #pragma unroll
        for (int kk = 0; kk < 4; kk++)
            #pragma unroll
            for (int nt = 0; nt < 4; nt++) {
                bf16x8 b = *(const bf16x8*)(smem + O_WP + (nt * 16 + ln) * SK128 + kk * 32 + 8 * qd);
                c[nt] = MFMA(am[kk], b, c[nt]);
            }
        const int m0 = w << 4;
        #pragma unroll
        for (int rg = 0; rg < 4; rg++) {
            const int node = nb0 + m0 + qd * 4 + rg;
            if (node < Nn) {
                __bf16* cp = ca + ((size_t)r * Nn + node) * HH;
                #pragma unroll
                for (int nt = 0; nt < 4; nt++)
                    cp[nt * 16 + ln] = (__bf16)c[nt][rg];
            }
        }
    }
}

// ---------------- node updater MLP (weights in LDS; CSR gather of contribs) ----------------
__global__ __launch_bounds__(NT, 2) void k_node(
    const float* __restrict__ nf,
    const float* __restrict__ bn1, const float* __restrict__ bn2, const float* __restrict__ bn3,
    const __bf16* __restrict__ wt, const __bf16* __restrict__ ca,
    const int* __restrict__ rowStart, const int* __restrict__ csrKey,
    float* __restrict__ out, int Nn)
{
    __shared__ __bf16 smem[NSMEM_ELEMS];
    const int nb0 = blockIdx.x * 64;
    const int tid = threadIdx.x;
    const int w = tid >> 6;
    const int lane = tid & 63;
    const int ln = lane & 15, qd = lane >> 4;
    const int m0 = w << 4;
    __bf16* act = smem + N_ACT + w * ABLK;

    stageRM<64, 128, SK128>(wt + WN1_OFF, smem + N_W1, tid);
    stageRM<64,  64, SK64 >(wt + WN2_OFF, smem + N_W2, tid);
    stageRM<128, 64, SK64 >(wt + WN3_OFF, smem + N_W3, tid);
    {
        const int m = tid >> 2, q = tid & 3;
        const int node = min(nb0 + m, Nn - 1);
        const float4* rp = (const float4*)(nf + (size_t)node * DD) + 8 * q;
        __bf16* xr = act + (m & 15) * SK128 + 32 * q;
        #pragma unroll
        for (int jj = 0; jj < 4; jj++) {
            float4 v0 = rp[2 * jj], v1 = rp[2 * jj + 1];
            bf16x8 p;
            p[0] = (__bf16)fmaxf(v0.x, 0.f); p[1] = (__bf16)fmaxf(v0.y, 0.f);
            p[2] = (__bf16)fmaxf(v0.z, 0.f); p[3] = (__bf16)fmaxf(v0.w, 0.f);
            p[4] = (__bf16)fmaxf(v1.x, 0.f); p[5] = (__bf16)fmaxf(v1.y, 0.f);
            p[6] = (__bf16)fmaxf(v1.z, 0.f); p[7] = (__bf16)fmaxf(v1.w, 0.f);
            *(bf16x8*)(xr + 8 * jj) = p;
        }
    }
    bf16x8 ax[4];
    #pragma unroll
    for (int i = 0; i < 4; i++)
        ax[i] = *(const bf16x8*)(act + ln * SK128 + i * 32 + 8 * qd);

    // CSR gather of contribs (4 independent chains), overlaps the barrier wait
    float agg[4][4] = {};
    #pragma unroll
    for (int rg = 0; rg < 4; rg++) {
        const int node = nb0 + m0 + qd * 4 + rg;
        if (node < Nn) {
            const int s0 = rowStart[node], s1 = rowStart[node + 1];
            for (int s = s0; s < s1; s++) {
                const int key = csrKey[s];
                const __bf16* cp = ca + (size_t)key * HH + ln;
                agg[rg][0] += (float)cp[0];
                agg[rg][1] += (float)cp[16];
                agg[rg][2] += (float)cp[32];
                agg[rg][3] += (float)cp[48];
            }
        }
    }
    __syncthreads();   // weights ready

    // GEMM1n: relu(relu(X) Wn1_0 + agg + bn1)  K=128 N=64
    {
        f32x4 c[4] = {};
        #pragma unroll
        for (int kk = 0; kk < 4; kk++)
            #pragma unroll
            for (int nt = 0; nt < 4; nt++) {
                bf16x8 b = *(const bf16x8*)(smem + N_W1 + (nt * 16 + ln) * SK128 + kk * 32 + 8 * qd);
                c[nt] = MFMA(ax[kk], b, c[nt]);
            }
        #pragma unroll
        for (int nt = 0; nt < 4; nt++) {
            float bv = bn1[nt * 16 + ln];
            #pragma unroll
            for (int rg = 0; rg < 4; rg++) {
                float v = c[nt][rg] + bv + agg[rg][nt];
                act[(qd * 4 + rg) * SK64 + nt * 16 + ln] = (__bf16)fmaxf(v, 0.f);
            }
        }
    }
    // GEMM2n: K=64 (H2 overlays H1)
    {
        bf16x8 a0 = *(const bf16x8*)(act + ln * SK64 + 0 + 8 * qd);
        bf16x8 a1 = *(const bf16x8*)(act + ln * SK64 + 32 + 8 * qd);
        f32x4 c[4] = {};
        #pragma unroll
        for (int nt = 0; nt < 4; nt++) {
            bf16x8 b0 = *(const bf16x8*)(smem + N_W2 + (nt * 16 + ln) * SK64 + 0 + 8 * qd);
            bf16x8 b1 = *(const bf16x8*)(smem + N_W2 + (nt * 16 + ln) * SK64 + 32 + 8 * qd);
            c[nt] = MFMA(a0, b0, c[nt]);
            c[nt] = MFMA(a1, b1, c[nt]);
        }
        #pragma unroll
        for (int nt = 0; nt < 4; nt++) {
            float bv = bn2[nt * 16 + ln];
            #pragma unroll
            for (int rg = 0; rg < 4; rg++) {
                float v = c[nt][rg] + bv;
                act[(qd * 4 + rg) * SK64 + nt * 16 + ln] = (__bf16)fmaxf(v, 0.f);
            }
        }
    }
    // GEMM3n: K=64 N=128 -> out (+bn3, no relu)
    {
        bf16x8 a0 = *(const bf16x8*)(act + ln * SK64 + 0 + 8 * qd);
        bf16x8 a1 = *(const bf16x8*)(act + ln * SK64 + 32 + 8 * qd);
        f32x4 c[8];
        #pragma unroll
        for (int nt = 0; nt < 8; nt++) {
            bf16x8 b0 = *(const bf16x8*)(smem + N_W3 + (nt * 16 + ln) * SK64 + 0 + 8 * qd);
            bf16x8 b1 = *(const bf16x8*)(smem + N_W3 + (nt * 16 + ln) * SK64 + 32 + 8 * qd);
            f32x4 acc = {};
            acc = MFMA(a0, b0, acc);
            acc = MFMA(a1, b1, acc);
            c[nt] = acc;
        }
        #pragma unroll
        for (int rg = 0; rg < 4; rg++) {
            const int node = nb0 + m0 + qd * 4 + rg;
            if (node < Nn) {
                float* op = out + (size_t)node * DD;
                #pragma unroll
                for (int nt = 0; nt < 8; nt++)
                    op[nt * 16 + ln] = c[nt][rg] + bn3[nt * 16 + ln];
            }
        }
    }
}

extern "C" void kernel_launch(void* const* d_in, const int* in_sizes, int n_in,
                              void* d_out, int out_size, void* d_ws, size_t ws_size,
                              hipStream_t stream) {
    const float* nf  = (const float*)d_in[0];
    const int*   es  = (const int*)d_in[1];
    const int*   ed  = (const int*)d_in[2];
    const int*   et  = (const int*)d_in[3];
    const float* Wr1 = (const float*)d_in[4];
    const float* br1 = (const float*)d_in[5];
    const float* Wr2 = (const float*)d_in[6];
    const float* br2 = (const float*)d_in[7];
    const float* Wr3 = (const float*)d_in[8];
    const float* br3 = (const float*)d_in[9];
    const float* Wn1 = (const float*)d_in[10];
    const float* bn1 = (const float*)d_in[11];
    const float* Wn2 = (const float*)d_in[12];
    const float* bn2 = (const float*)d_in[13];
    const float* Wn3 = (const float*)d_in[14];
    const float* bn3 = (const float*)d_in[15];
    float* out = (float*)d_out;

    const int Nn = in_sizes[0] / DD;   // 50000
    const int E  = in_sizes[1];        // 200000
    const int NB = (Nn + 1023) / 1024; // <=64

    int* p = (int*)d_ws;
    int* dstCnt    = p;                 p += Nn;      // zeroed
    int* dstCursor = p;                 p += Nn;
    int* rowStart  = p;                 p += Nn + 1;
    int* blkSum    = p;                 p += 64;
    int* blkOff    = p;                 p += 64;
    int* csrKey    = p;                 p += E;
    p += ((8 - ((p - (int*)d_ws) & 7)) & 7);          // 32B-align
    __bf16* wbf = (__bf16*)p;           p += (WT_TOTAL + 1) / 2;
    __bf16* ca  = (__bf16*)p;                          // RR*Nn*HH bf16 = 25.6 MB

    hipFuncSetAttribute((const void*)k_dense,
                        hipFuncAttributeMaxDynamicSharedMemorySize,
                        DSMEM_ELEMS * (int)sizeof(__bf16));

    hipMemsetAsync((void*)dstCnt, 0, (size_t)Nn * sizeof(int), stream);

    const int nb = (E + NT - 1) / NT;
    k_hist <<<nb, NT, 0, stream>>>(ed, dstCnt, E);
    k_bsum <<<NB, 256, 0, stream>>>(dstCnt, blkSum, Nn);
    k_mid  <<<1, 64, 0, stream>>>(blkSum, blkOff, rowStart, NB, Nn, E);
    k_wout <<<NB, 256, 0, stream>>>(dstCnt, blkOff, rowStart, dstCursor, Nn);
    k_place<<<nb, NT, 0, stream>>>(et, ed, es, dstCursor, csrKey, E, Nn);
    k_prep <<<(WT_TOTAL + NT - 1) / NT, NT, 0, stream>>>(Wr1, Wr2, Wr3, Wn1, Wn2, Wn3, wbf);

    dim3 gd((Nn + 63) / 64, RR);
    k_dense<<<gd, NT, DSMEM_ELEMS * sizeof(__bf16), stream>>>(nf, br1, br2, br3, wbf, ca, Nn);
    k_node <<<(Nn + 63) / 64, NT, 0, stream>>>(nf, bn1, bn2, bn3, wbf, ca, rowStart, csrKey, out, Nn);
}